// Round 3
// baseline (4092.564 us; speedup 1.0000x reference)
//
#include <hip/hip_runtime.h>
#include <math.h>

#define BATCH   256
#define SEQ     128
#define DMODEL  384
#define DSTATE  64
#define DINNER  768
#define NHEADS  12
#define HEADDIM 64
#define CONVDIM 896
#define DPROJ   1676
#define OUTDIM  60
#define MTOT    (BATCH*SEQ)   // 32768

__device__ __forceinline__ float siluf(float x){ return x / (1.f + expf(-x)); }
__device__ __forceinline__ float softplusf(float x){ return fmaxf(x,0.f) + log1pf(expf(-fabsf(x))); }

// x = emb + positional encoding (computed inline, matches np float32 recipe)
__global__ void add_pe_kernel(const float* __restrict__ emb, float* __restrict__ x){
  int idx = blockIdx.x*256 + threadIdx.x;        // total = MTOT*DMODEL, exact
  int d = idx % DMODEL;
  int l = (idx / DMODEL) % SEQ;
  int i = d >> 1;
  float div = expf((float)(2*i) * (-9.210340371976184f/384.f)); // -ln(10000)/384
  float arg = (float)l * div;
  float pe = (d & 1) ? cosf(arg) : sinf(arg);
  x[idx] = emb[idx] + pe;
}

// per-row mean / rstd for LayerNorm (fused into GEMM A-load)
__global__ void __launch_bounds__(256) ln_stats_kernel(const float* __restrict__ x,
                                                       float* __restrict__ mu, float* __restrict__ rstd){
  int wave = threadIdx.x >> 6, lane = threadIdx.x & 63;
  int m = blockIdx.x*4 + wave;
  const float* row = x + (size_t)m*DMODEL;
  float s=0.f, s2=0.f;
  #pragma unroll
  for (int j=0;j<6;j++){
    float v = row[lane + 64*j];
    s += v; s2 += v*v;
  }
  #pragma unroll
  for (int off=32;off;off>>=1){ s += __shfl_xor(s,off,64); s2 += __shfl_xor(s2,off,64); }
  if (lane==0){
    float m1 = s * (1.f/384.f);
    float var = s2 * (1.f/384.f) - m1*m1;
    mu[m] = m1;
    rstd[m] = rsqrtf(var + 1e-5f);
  }
}

// C[m,n] = sum_k A'[m,k] * W[n,k]   (A' = LN(A) if fuse_ln; += C_old if res_add)
// 64x64 block tile, 256 threads, 4x4 micro-tile, K-tile 16 in LDS.
__global__ void __launch_bounds__(256) gemm_tile(
  const float* __restrict__ A, const float* __restrict__ W, float* __restrict__ C,
  int M, int N, int K,
  const float* __restrict__ mu, const float* __restrict__ rstd,
  const float* __restrict__ lnw, const float* __restrict__ lnb,
  int fuse_ln, int res_add)
{
  __shared__ float As[16][68];
  __shared__ float Ws[16][68];
  const int tid = threadIdx.x;
  const int m0 = blockIdx.y*64, n0 = blockIdx.x*64;
  const int lr = tid >> 2;          // 0..63 tile row for loads
  const int lk = (tid & 3) * 4;     // k sub-offset
  const int tx = tid & 15, ty = tid >> 4;
  float acc[4][4] = {{0.f}};
  float rmu = 0.f, rrs = 1.f;
  if (fuse_ln){ rmu = mu[m0+lr]; rrs = rstd[m0+lr]; }
  const float* arow = A + (size_t)(m0+lr)*K;
  const int wr = n0 + lr;
  const float* wrow = W + (size_t)wr*K;
  for (int k0=0; k0<K; k0+=16){
    float4 av = *(const float4*)(arow + k0 + lk);
    if (fuse_ln){
      const float4 lw = *(const float4*)(lnw + k0 + lk);
      const float4 lb = *(const float4*)(lnb + k0 + lk);
      av.x = (av.x - rmu)*rrs*lw.x + lb.x;
      av.y = (av.y - rmu)*rrs*lw.y + lb.y;
      av.z = (av.z - rmu)*rrs*lw.z + lb.z;
      av.w = (av.w - rmu)*rrs*lw.w + lb.w;
    }
    float4 wv = make_float4(0.f,0.f,0.f,0.f);
    if (wr < N) wv = *(const float4*)(wrow + k0 + lk);
    As[lk+0][lr]=av.x; As[lk+1][lr]=av.y; As[lk+2][lr]=av.z; As[lk+3][lr]=av.w;
    Ws[lk+0][lr]=wv.x; Ws[lk+1][lr]=wv.y; Ws[lk+2][lr]=wv.z; Ws[lk+3][lr]=wv.w;
    __syncthreads();
    #pragma unroll
    for (int k=0;k<16;k++){
      float4 a4 = *(const float4*)&As[k][ty*4];
      float4 b4 = *(const float4*)&Ws[k][tx*4];
      float a[4] = {a4.x,a4.y,a4.z,a4.w};
      float bb[4] = {b4.x,b4.y,b4.z,b4.w};
      #pragma unroll
      for (int i=0;i<4;i++)
        #pragma unroll
        for (int j=0;j<4;j++)
          acc[i][j] = fmaf(a[i], bb[j], acc[i][j]);
    }
    __syncthreads();
  }
  #pragma unroll
  for (int i=0;i<4;i++){
    int m = m0 + ty*4 + i;
    float* crow = C + (size_t)m*N;
    #pragma unroll
    for (int j=0;j<4;j++){
      int n = n0 + tx*4 + j;
      if (n < N){
        float v = acc[i][j];
        if (res_add) v += crow[n];
        crow[n] = v;
      }
    }
  }
}

// depthwise causal conv (width 4) + bias + SiLU over the xBC slice of zx (chunk-local)
__global__ void conv_silu_kernel(const float* __restrict__ zx, const float* __restrict__ cw,
                                 const float* __restrict__ cb, float* __restrict__ xBC){
  int idx = blockIdx.x*256 + threadIdx.x;   // total = Mc*CONVDIM, exact
  int c = idx % CONVDIM;
  int lm = idx / CONVDIM;                   // chunk-local row (chunk starts at batch boundary)
  int l = lm % SEQ;
  float acc = cb[c];
  const float* wc = cw + c*4;
  const float* col = zx + (size_t)lm*DPROJ + 768 + c;
  #pragma unroll
  for (int k=0;k<4;k++){
    int dl = k - 3;                          // source offset l+k-3
    if (l + dl >= 0)
      acc = fmaf(col[(long)dl*DPROJ], wc[k], acc);
  }
  xBC[idx] = siluf(acc);
}

// dt = softplus(zx[..., -12:] + dt_bias)
__global__ void dt_kernel(const float* __restrict__ zx, const float* __restrict__ dtb,
                          float* __restrict__ dt){
  int idx = blockIdx.x*256 + threadIdx.x;   // total = Mc*NHEADS, exact
  int h = idx % NHEADS;
  int m = idx / NHEADS;
  float v = zx[(size_t)m*DPROJ + 1664 + h] + dtb[h];
  dt[idx] = softplusf(v);
}

// sequential SSM scan: one wave per (batch, head); lane = p; h-state [64] in regs.
__global__ void __launch_bounds__(256) scan_kernel(
  const float* __restrict__ xBC, const float* __restrict__ dt,
  const float* __restrict__ A_log, const float* __restrict__ Dp,
  float* __restrict__ y)
{
  const int b = blockIdx.x;                 // chunk-local batch
  const int wave = threadIdx.x >> 6;
  const int lane = threadIdx.x & 63;
  const int h = blockIdx.y*4 + wave;
  const float A = -expf(A_log[h]);
  const float Dh = Dp[h];
  float hs[64];
  #pragma unroll
  for (int n=0;n<64;n++) hs[n] = 0.f;
  __shared__ float Bs[2][64];
  __shared__ float Cs[2][64];
  const float* xb  = xBC + (size_t)b*SEQ*CONVDIM;
  const float* dtb = dt  + (size_t)b*SEQ*NHEADS;
  float* yb = y + (size_t)b*SEQ*DINNER;
  if (threadIdx.x < 64)        Bs[0][threadIdx.x]      = xb[768 + threadIdx.x];
  else if (threadIdx.x < 128)  Cs[0][threadIdx.x - 64] = xb[832 + threadIdx.x - 64];
  __syncthreads();
  for (int t=0; t<SEQ; t++){
    const float xp  = xb[t*CONVDIM + h*HEADDIM + lane];
    const float dtv = dtb[t*NHEADS + h];
    const float dA  = expf(dtv * A);
    const float coef = dtv * xp;
    const float* Bb = Bs[t&1];
    const float* Cb = Cs[t&1];
    float yacc = 0.f;
    #pragma unroll
    for (int n=0;n<64;n+=4){
      float4 b4 = *(const float4*)&Bb[n];
      float4 c4 = *(const float4*)&Cb[n];
      hs[n+0] = fmaf(hs[n+0], dA, coef*b4.x); yacc = fmaf(hs[n+0], c4.x, yacc);
      hs[n+1] = fmaf(hs[n+1], dA, coef*b4.y); yacc = fmaf(hs[n+1], c4.y, yacc);
      hs[n+2] = fmaf(hs[n+2], dA, coef*b4.z); yacc = fmaf(hs[n+2], c4.z, yacc);
      hs[n+3] = fmaf(hs[n+3], dA, coef*b4.w); yacc = fmaf(hs[n+3], c4.w, yacc);
    }
    yb[t*DINNER + h*HEADDIM + lane] = yacc + Dh*xp;
    if (t+1 < SEQ){
      const float* src = xb + (t+1)*CONVDIM;
      const int tb = (t+1)&1;
      if (threadIdx.x < 64)       Bs[tb][threadIdx.x]      = src[768 + threadIdx.x];
      else if (threadIdx.x < 128) Cs[tb][threadIdx.x - 64] = src[832 + threadIdx.x - 64];
    }
    __syncthreads();
  }
}

// g = y * silu(z); g *= rsqrt(mean(g^2)+eps) * norm_w   (in-place into y)
__global__ void __launch_bounds__(256) gate_rms_kernel(const float* __restrict__ zx,
                                                       const float* __restrict__ normw,
                                                       float* __restrict__ y){
  int m = blockIdx.x;
  int tid = threadIdx.x;
  float g[3];
  float ss = 0.f;
  const float* zrow = zx + (size_t)m*DPROJ;
  float* yrow = y + (size_t)m*DINNER;
  #pragma unroll
  for (int j=0;j<3;j++){
    int e = tid + 256*j;
    float z = zrow[e];
    float gv = yrow[e] * siluf(z);
    g[j] = gv;
    ss += gv*gv;
  }
  #pragma unroll
  for (int off=32;off;off>>=1) ss += __shfl_xor(ss,off,64);
  __shared__ float red[4];
  if ((tid&63)==0) red[tid>>6] = ss;
  __syncthreads();
  float tot = red[0]+red[1]+red[2]+red[3];
  float rms = rsqrtf(tot*(1.f/768.f) + 1e-5f);
  #pragma unroll
  for (int j=0;j<3;j++){
    int e = tid + 256*j;
    yrow[e] = g[j]*rms*normw[e];
  }
}

// final LN on last timestep + 60x384 projection
__global__ void __launch_bounds__(64) final_kernel(const float* __restrict__ x,
  const float* __restrict__ onw, const float* __restrict__ onb,
  const float* __restrict__ pw, const float* __restrict__ pb, float* __restrict__ out)
{
  int b = blockIdx.x;
  int lane = threadIdx.x;
  const float* row = x + ((size_t)b*SEQ + (SEQ-1))*DMODEL;
  float s=0.f, s2=0.f;
  float v[6];
  #pragma unroll
  for (int j=0;j<6;j++){ v[j] = row[lane + 64*j]; s += v[j]; s2 += v[j]*v[j]; }
  #pragma unroll
  for (int off=32;off;off>>=1){ s += __shfl_xor(s,off,64); s2 += __shfl_xor(s2,off,64); }
  float m1 = s*(1.f/384.f);
  float var = s2*(1.f/384.f) - m1*m1;
  float rstd = rsqrtf(var + 1e-5f);
  __shared__ float xn[384];
  #pragma unroll
  for (int j=0;j<6;j++){
    int d = lane + 64*j;
    xn[d] = (v[j]-m1)*rstd*onw[d] + onb[d];
  }
  __syncthreads();
  if (lane < OUTDIM){
    const float* wrow = pw + lane*DMODEL;
    float acc = pb[lane];
    #pragma unroll 4
    for (int d=0; d<DMODEL; d+=4){
      float4 xv = *(const float4*)&xn[d];
      float4 wv = *(const float4*)&wrow[d];
      acc += xv.x*wv.x + xv.y*wv.y + xv.z*wv.z + xv.w*wv.w;
    }
    out[b*OUTDIM + lane] = acc;
  }
}

extern "C" void kernel_launch(void* const* d_in, const int* in_sizes, int n_in,
                              void* d_out, int out_size, void* d_ws, size_t ws_size,
                              hipStream_t stream){
  const float* emb        = (const float*)d_in[0];
  const float* in_proj_w  = (const float*)d_in[1];
  const float* conv_w     = (const float*)d_in[2];
  const float* conv_b     = (const float*)d_in[3];
  const float* dt_bias    = (const float*)d_in[4];
  const float* A_log      = (const float*)d_in[5];
  const float* Dp         = (const float*)d_in[6];
  const float* mnw        = (const float*)d_in[7];
  const float* out_proj_w = (const float*)d_in[8];
  const float* ln_w       = (const float*)d_in[9];
  const float* ln_b       = (const float*)d_in[10];
  const float* onw        = (const float*)d_in[11];
  const float* onb        = (const float*)d_in[12];
  const float* pw         = (const float*)d_in[13];
  const float* pb         = (const float*)d_in[14];
  float* out = (float*)d_out;

  // ---- adaptive workspace layout ----
  // fixed: x (full batch, residual stream) + LN stats
  // chunked (CB batches = Mc rows): zx, xBC, dt, y  at 13408 B/row
  const size_t XBYTES = (size_t)MTOT*DMODEL*4;        // 50,331,648
  const size_t STATB  = (size_t)MTOT*4;               // 131,072 each
  const size_t fixed  = XBYTES + 2*STATB;
  int CB = 256;
  while (CB > 1 && fixed + (size_t)CB*SEQ*13408ull > ws_size) CB >>= 1;
  const int Mc = CB*SEQ;
  const int nchunks = BATCH / CB;

  char* p = (char*)d_ws;
  float* x    = (float*)p;  p += XBYTES;
  float* mu   = (float*)p;  p += STATB;
  float* rstd = (float*)p;  p += STATB;
  float* zx   = (float*)p;  p += (size_t)Mc*DPROJ*4;
  float* xBC  = (float*)p;  p += (size_t)Mc*CONVDIM*4;
  float* dt   = (float*)p;  p += (size_t)Mc*NHEADS*4;
  float* y    = (float*)p;

  add_pe_kernel<<<MTOT*DMODEL/256,256,0,stream>>>(emb, x);
  for (int i=0;i<2;i++){
    ln_stats_kernel<<<MTOT/4,256,0,stream>>>(x, mu, rstd);
    for (int c=0;c<nchunks;c++){
      const float* xc = x + (size_t)c*Mc*DMODEL;
      dim3 g1(27, Mc/64);
      gemm_tile<<<g1,256,0,stream>>>(xc, in_proj_w + (size_t)i*DPROJ*DMODEL, zx,
          Mc, DPROJ, DMODEL, mu + (size_t)c*Mc, rstd + (size_t)c*Mc,
          ln_w+(size_t)i*DMODEL, ln_b+(size_t)i*DMODEL, 1, 0);
      conv_silu_kernel<<<Mc*CONVDIM/256,256,0,stream>>>(zx, conv_w + (size_t)i*CONVDIM*4,
          conv_b + (size_t)i*CONVDIM, xBC);
      dt_kernel<<<Mc*NHEADS/256,256,0,stream>>>(zx, dt_bias + (size_t)i*NHEADS, dt);
      dim3 gs(CB,3);
      scan_kernel<<<gs,256,0,stream>>>(xBC, dt, A_log + (size_t)i*NHEADS, Dp + (size_t)i*NHEADS, y);
      gate_rms_kernel<<<Mc,256,0,stream>>>(zx, mnw + (size_t)i*DINNER, y);
      dim3 g2(6, Mc/64);
      gemm_tile<<<g2,256,0,stream>>>(y, out_proj_w + (size_t)i*DMODEL*DINNER, (float*)xc,
          Mc, DMODEL, DINNER, nullptr, nullptr, nullptr, nullptr, 0, 1);
    }
  }
  final_kernel<<<BATCH,64,0,stream>>>(x, onw, onb, pw, pb, out);
}

// Round 4
// 1507.883 us; speedup vs baseline: 2.7141x; 2.7141x over previous
//
#include <hip/hip_runtime.h>
#include <math.h>

#define BATCH   256
#define SEQ     128
#define DMODEL  384
#define DSTATE  64
#define DINNER  768
#define NHEADS  12
#define HEADDIM 64
#define CONVDIM 896
#define DPROJ   1676
#define N1PAD   1792
#define OUTDIM  60
#define MTOT    (BATCH*SEQ)   // 32768

typedef unsigned short u16;
typedef short bf16x8 __attribute__((ext_vector_type(8)));
typedef float f32x4 __attribute__((ext_vector_type(4)));

#define ASG __attribute__((address_space(1)))
#define ASL __attribute__((address_space(3)))

__device__ __forceinline__ float siluf(float x){ return x / (1.f + expf(-x)); }
__device__ __forceinline__ float softplusf(float x){ return fmaxf(x,0.f) + log1pf(expf(-fabsf(x))); }
__device__ __forceinline__ u16 f2bf(float x){
  union { float f; unsigned int u; } c; c.f = x;
  unsigned int r = c.u + 0x7FFFu + ((c.u >> 16) & 1u);
  return (u16)(r >> 16);
}
__device__ __forceinline__ float bf2f(u16 u){
  union { unsigned int u; float f; } c; c.u = ((unsigned int)u) << 16;
  return c.f;
}

// x = emb + positional encoding
__global__ void add_pe_kernel(const float* __restrict__ emb, float* __restrict__ x){
  int idx = blockIdx.x*256 + threadIdx.x;
  int d = idx % DMODEL;
  int l = (idx / DMODEL) % SEQ;
  int i = d >> 1;
  float div = expf((float)(2*i) * (-9.210340371976184f/384.f));
  float arg = (float)l * div;
  float pe = (d & 1) ? cosf(arg) : sinf(arg);
  x[idx] = emb[idx] + pe;
}

// weight conversions (per layer, each call)
__global__ void wconv_in_kernel(const float* __restrict__ w, u16* __restrict__ o){
  int idx = blockIdx.x*256 + threadIdx.x;       // N1PAD*384 total
  int n = idx / DMODEL;
  o[idx] = (n < DPROJ) ? f2bf(w[idx - (n-n)*0 + 0 + (size_t)0 + (n < DPROJ ? 0 : 0)]) : (u16)0;
}
// NOTE: simple form below (kept separate to avoid the confusing expression above)
__global__ void wconv_in2_kernel(const float* __restrict__ w, u16* __restrict__ o){
  int idx = blockIdx.x*256 + threadIdx.x;       // N1PAD*DMODEL total
  int n = idx / DMODEL, k = idx % DMODEL;
  o[idx] = (n < DPROJ) ? f2bf(w[(size_t)n*DMODEL + k]) : (u16)0;
}
__global__ void wconv_out_kernel(const float* __restrict__ w, u16* __restrict__ o){
  int idx = blockIdx.x*256 + threadIdx.x;       // 384*768 total
  o[idx] = f2bf(w[idx]);
}

// xbf = bf16( LN(x)*lnw + lnb ), one wave per row
__global__ void __launch_bounds__(256) ln_bf_kernel(const float* __restrict__ x,
    const float* __restrict__ lnw, const float* __restrict__ lnb, u16* __restrict__ xbf){
  int wave = threadIdx.x >> 6, lane = threadIdx.x & 63;
  int m = blockIdx.x*4 + wave;
  const float* row = x + (size_t)m*DMODEL;
  float v[6], s=0.f, s2=0.f;
  #pragma unroll
  for (int j=0;j<6;j++){ v[j] = row[lane + 64*j]; s += v[j]; s2 += v[j]*v[j]; }
  #pragma unroll
  for (int off=32;off;off>>=1){ s += __shfl_xor(s,off,64); s2 += __shfl_xor(s2,off,64); }
  float m1 = s * (1.f/384.f);
  float var = s2 * (1.f/384.f) - m1*m1;
  float rstd = rsqrtf(var + 1e-5f);
  u16* orow = xbf + (size_t)m*DMODEL;
  #pragma unroll
  for (int j=0;j<6;j++){
    int d = lane + 64*j;
    orow[d] = f2bf((v[j]-m1)*rstd*lnw[d] + lnb[d]);
  }
}

// bf16 MFMA GEMM: C[m,n] = sum_k A[m,k]*W[n,k]; 128x128 tile, BK=64, 4 waves.
// MODE 0: in-proj epilogue (split z/xBCraw/dt);  MODE 1: out-proj (+= residual f32)
template<int MODE>
__global__ void __launch_bounds__(256) gemm_bf16(
    const u16* __restrict__ A, const u16* __restrict__ W, const int K,
    u16* __restrict__ zo, u16* __restrict__ xbcro, float* __restrict__ dto,
    const float* __restrict__ dt_bias, float* __restrict__ xres)
{
  __shared__ __align__(16) u16 As[128*64];
  __shared__ __align__(16) u16 Bs[128*64];
  const int tid = threadIdx.x;
  const int l = tid & 63;
  const int w = tid >> 6;
  const int wm = w >> 1, wn = w & 1;
  const int m0 = blockIdx.y * 128, n0 = blockIdx.x * 128;

  f32x4 acc[4][4];
  #pragma unroll
  for (int i=0;i<4;i++)
    #pragma unroll
    for (int j=0;j<4;j++)
      acc[i][j] = (f32x4){0.f,0.f,0.f,0.f};

  const int grow = tid >> 3;            // 0..31
  const int gcol = (tid & 7) * 8;
  const u16* Abase = A + (size_t)(m0 + grow)*K + gcol;
  const u16* Wbase = W + (size_t)(n0 + grow)*K + gcol;
  u16* asb = &As[w*512];                // wave-uniform LDS bases (lane*16B added by HW)
  u16* bsb = &Bs[w*512];

  for (int k0 = 0; k0 < K; k0 += 64){
    #pragma unroll
    for (int i=0;i<4;i++){
      __builtin_amdgcn_global_load_lds((const ASG void*)(Abase + (size_t)i*32*K + k0),
                                       (ASL void*)(asb + i*2048), 16, 0, 0);
      __builtin_amdgcn_global_load_lds((const ASG void*)(Wbase + (size_t)i*32*K + k0),
                                       (ASL void*)(bsb + i*2048), 16, 0, 0);
    }
    __syncthreads();
    #pragma unroll
    for (int ks=0; ks<64; ks+=32){
      const int ko = ks + ((l>>4)<<3);
      const int rr = l & 15;
      bf16x8 af[4], bfv[4];
      #pragma unroll
      for (int f=0; f<4; f++){
        af[f]  = *(const bf16x8*)&As[(wm*64 + f*16 + rr)*64 + ko];
        bfv[f] = *(const bf16x8*)&Bs[(wn*64 + f*16 + rr)*64 + ko];
      }
      #pragma unroll
      for (int fi=0; fi<4; fi++)
        #pragma unroll
        for (int fj=0; fj<4; fj++)
          acc[fi][fj] = __builtin_amdgcn_mfma_f32_16x16x32_bf16(af[fi], bfv[fj], acc[fi][fj], 0, 0, 0);
    }
    __syncthreads();
  }

  const int cg = l & 15;
  const int rb = (l >> 4) * 4;
  #pragma unroll
  for (int fi=0; fi<4; fi++){
    #pragma unroll
    for (int r=0; r<4; r++){
      const int m = m0 + wm*64 + fi*16 + rb + r;
      #pragma unroll
      for (int fj=0; fj<4; fj++){
        const int n = n0 + wn*64 + fj*16 + cg;
        float v = acc[fi][fj][r];
        if (MODE == 0){
          if (n < DINNER)            zo[(size_t)m*DINNER + n] = f2bf(v);
          else if (n < DINNER+CONVDIM) xbcro[(size_t)m*CONVDIM + n - DINNER] = f2bf(v);
          else if (n < DPROJ)        dto[(size_t)m*NHEADS + n - (DINNER+CONVDIM)] =
                                        softplusf(v + dt_bias[n - (DINNER+CONVDIM)]);
        } else {
          xres[(size_t)m*DMODEL + n] += v;
        }
      }
    }
  }
}

// depthwise causal conv (width 4) + bias + SiLU, bf16 in/out
__global__ void conv_silu_bf_kernel(const u16* __restrict__ xbcr, const float* __restrict__ cw,
                                    const float* __restrict__ cb, u16* __restrict__ xbc){
  int idx = blockIdx.x*256 + threadIdx.x;   // Mc*CONVDIM total
  int c = idx % CONVDIM;
  int lm = idx / CONVDIM;
  int lq = lm % SEQ;
  float acc = cb[c];
  const float* wc = cw + c*4;
  const u16* col = xbcr + (size_t)lm*CONVDIM + c;
  #pragma unroll
  for (int k=0;k<4;k++){
    int dl = k - 3;
    if (lq + dl >= 0)
      acc = fmaf(bf2f(col[(long)dl*CONVDIM]), wc[k], acc);
  }
  xbc[idx] = f2bf(siluf(acc));
}

// sequential SSM scan: one wave per (batch, head); bf16 in, bf16 out, f32 state
__global__ void __launch_bounds__(256) scan_bf_kernel(
  const u16* __restrict__ xbc, const float* __restrict__ dtb,
  const float* __restrict__ A_log, const float* __restrict__ Dp,
  u16* __restrict__ y)
{
  const int b = blockIdx.x;
  const int wave = threadIdx.x >> 6;
  const int lane = threadIdx.x & 63;
  const int h = blockIdx.y*4 + wave;
  const float A = -expf(A_log[h]);
  const float Dh = Dp[h];
  float hs[64];
  #pragma unroll
  for (int n=0;n<64;n++) hs[n] = 0.f;
  __shared__ float Bsm[2][64];
  __shared__ float Csm[2][64];
  const u16* xb   = xbc + (size_t)b*SEQ*CONVDIM;
  const float* dr = dtb + (size_t)b*SEQ*NHEADS;
  u16* yb = y + (size_t)b*SEQ*DINNER;
  if (threadIdx.x < 64)        Bsm[0][threadIdx.x]      = bf2f(xb[DINNER + threadIdx.x]);
  else if (threadIdx.x < 128)  Csm[0][threadIdx.x - 64] = bf2f(xb[DINNER + DSTATE + threadIdx.x - 64]);
  __syncthreads();
  for (int t=0; t<SEQ; t++){
    const float xp  = bf2f(xb[t*CONVDIM + h*HEADDIM + lane]);
    const float dtv = dr[t*NHEADS + h];
    const float dA  = expf(dtv * A);
    const float coef = dtv * xp;
    const float* Bb = Bsm[t&1];
    const float* Cb = Csm[t&1];
    float yacc = 0.f;
    #pragma unroll
    for (int n=0;n<64;n+=4){
      float4 b4 = *(const float4*)&Bb[n];
      float4 c4 = *(const float4*)&Cb[n];
      hs[n+0] = fmaf(hs[n+0], dA, coef*b4.x); yacc = fmaf(hs[n+0], c4.x, yacc);
      hs[n+1] = fmaf(hs[n+1], dA, coef*b4.y); yacc = fmaf(hs[n+1], c4.y, yacc);
      hs[n+2] = fmaf(hs[n+2], dA, coef*b4.z); yacc = fmaf(hs[n+2], c4.z, yacc);
      hs[n+3] = fmaf(hs[n+3], dA, coef*b4.w); yacc = fmaf(hs[n+3], c4.w, yacc);
    }
    yb[t*DINNER + h*HEADDIM + lane] = f2bf(yacc + Dh*xp);
    if (t+1 < SEQ){
      const u16* src = xb + (t+1)*CONVDIM;
      const int tb = (t+1)&1;
      if (threadIdx.x < 64)       Bsm[tb][threadIdx.x]      = bf2f(src[DINNER + threadIdx.x]);
      else if (threadIdx.x < 128) Csm[tb][threadIdx.x - 64] = bf2f(src[DINNER + DSTATE + threadIdx.x - 64]);
    }
    __syncthreads();
  }
}

// g = y * silu(z); g *= rsqrt(mean(g^2)+eps) * norm_w  (bf16 in-place in y)
__global__ void __launch_bounds__(256) gate_rms_bf_kernel(const u16* __restrict__ z,
    const float* __restrict__ normw, u16* __restrict__ y){
  int m = blockIdx.x;
  int tid = threadIdx.x;
  float g[3];
  float ss = 0.f;
  const u16* zrow = z + (size_t)m*DINNER;
  u16* yrow = y + (size_t)m*DINNER;
  #pragma unroll
  for (int j=0;j<3;j++){
    int e = tid + 256*j;
    float zv = bf2f(zrow[e]);
    float gv = bf2f(yrow[e]) * siluf(zv);
    g[j] = gv;
    ss += gv*gv;
  }
  #pragma unroll
  for (int off=32;off;off>>=1) ss += __shfl_xor(ss,off,64);
  __shared__ float red[4];
  if ((tid&63)==0) red[tid>>6] = ss;
  __syncthreads();
  float tot = red[0]+red[1]+red[2]+red[3];
  float rms = rsqrtf(tot*(1.f/768.f) + 1e-5f);
  #pragma unroll
  for (int j=0;j<3;j++){
    int e = tid + 256*j;
    yrow[e] = f2bf(g[j]*rms*normw[e]);
  }
}

// final LN on last timestep + 60x384 projection (f32)
__global__ void __launch_bounds__(64) final_kernel(const float* __restrict__ x,
  const float* __restrict__ onw, const float* __restrict__ onb,
  const float* __restrict__ pw, const float* __restrict__ pb, float* __restrict__ out)
{
  int b = blockIdx.x;
  int lane = threadIdx.x;
  const float* row = x + ((size_t)b*SEQ + (SEQ-1))*DMODEL;
  float s=0.f, s2=0.f;
  float v[6];
  #pragma unroll
  for (int j=0;j<6;j++){ v[j] = row[lane + 64*j]; s += v[j]; s2 += v[j]*v[j]; }
  #pragma unroll
  for (int off=32;off;off>>=1){ s += __shfl_xor(s,off,64); s2 += __shfl_xor(s2,off,64); }
  float m1 = s*(1.f/384.f);
  float var = s2*(1.f/384.f) - m1*m1;
  float rstd = rsqrtf(var + 1e-5f);
  __shared__ float xn[384];
  #pragma unroll
  for (int j=0;j<6;j++){
    int d = lane + 64*j;
    xn[d] = (v[j]-m1)*rstd*onw[d] + onb[d];
  }
  __syncthreads();
  if (lane < OUTDIM){
    const float* wrow = pw + lane*DMODEL;
    float acc = pb[lane];
    #pragma unroll 4
    for (int d=0; d<DMODEL; d+=4){
      float4 xv = *(const float4*)&xn[d];
      float4 wv = *(const float4*)&wrow[d];
      acc += xv.x*wv.x + xv.y*wv.y + xv.z*wv.z + xv.w*wv.w;
    }
    out[b*OUTDIM + lane] = acc;
  }
}

extern "C" void kernel_launch(void* const* d_in, const int* in_sizes, int n_in,
                              void* d_out, int out_size, void* d_ws, size_t ws_size,
                              hipStream_t stream){
  const float* emb        = (const float*)d_in[0];
  const float* in_proj_w  = (const float*)d_in[1];
  const float* conv_w     = (const float*)d_in[2];
  const float* conv_b     = (const float*)d_in[3];
  const float* dt_bias    = (const float*)d_in[4];
  const float* A_log      = (const float*)d_in[5];
  const float* Dp         = (const float*)d_in[6];
  const float* mnw        = (const float*)d_in[7];
  const float* out_proj_w = (const float*)d_in[8];
  const float* ln_w       = (const float*)d_in[9];
  const float* ln_b       = (const float*)d_in[10];
  const float* onw        = (const float*)d_in[11];
  const float* onb        = (const float*)d_in[12];
  const float* pw         = (const float*)d_in[13];
  const float* pb         = (const float*)d_in[14];
  float* out = (float*)d_out;

  // ---- adaptive workspace ----
  // fixed: x f32 (50.33MB), xbf bf16 (25.17MB), wbf_in (1.38MB), wbf_out (0.59MB)
  // per row (chunked): z 1536 + xbcr 1792 + xbc 1792 + dt 48 + y 1536 = 6704 B
  const size_t XB    = (size_t)MTOT*DMODEL*4;
  const size_t XBFB  = (size_t)MTOT*DMODEL*2;
  const size_t WINB  = (size_t)N1PAD*DMODEL*2;
  const size_t WOUTB = (size_t)DMODEL*DINNER*2;
  const size_t fixed = XB + XBFB + WINB + WOUTB;
  int CB = 256;
  while (CB > 1 && fixed + (size_t)CB*SEQ*6704ull > ws_size) CB >>= 1;
  const int Mc = CB*SEQ;
  const int nchunks = BATCH / CB;

  char* p = (char*)d_ws;
  float* x      = (float*)p;  p += XB;
  u16*   xbf    = (u16*)p;    p += XBFB;
  u16*   wbfin  = (u16*)p;    p += WINB;
  u16*   wbfout = (u16*)p;    p += WOUTB;
  u16*   z      = (u16*)p;    p += (size_t)Mc*DINNER*2;
  u16*   xbcr   = (u16*)p;    p += (size_t)Mc*CONVDIM*2;
  u16*   xbc    = (u16*)p;    p += (size_t)Mc*CONVDIM*2;
  float* dt     = (float*)p;  p += (size_t)Mc*NHEADS*4;
  u16*   y      = (u16*)p;

  add_pe_kernel<<<MTOT*DMODEL/256,256,0,stream>>>(emb, x);
  for (int i=0;i<2;i++){
    wconv_in2_kernel<<<N1PAD*DMODEL/256,256,0,stream>>>(in_proj_w + (size_t)i*DPROJ*DMODEL, wbfin);
    wconv_out_kernel<<<DMODEL*DINNER/256,256,0,stream>>>(out_proj_w + (size_t)i*DMODEL*DINNER, wbfout);
    ln_bf_kernel<<<MTOT/4,256,0,stream>>>(x, ln_w + (size_t)i*DMODEL, ln_b + (size_t)i*DMODEL, xbf);
    for (int c=0;c<nchunks;c++){
      const u16* ac = xbf + (size_t)c*Mc*DMODEL;
      float*     xc = x   + (size_t)c*Mc*DMODEL;
      dim3 g1(N1PAD/128, Mc/128);
      gemm_bf16<0><<<g1,256,0,stream>>>(ac, wbfin, DMODEL, z, xbcr, dt,
                                        dt_bias + (size_t)i*NHEADS, nullptr);
      conv_silu_bf_kernel<<<Mc*CONVDIM/256,256,0,stream>>>(xbcr, conv_w + (size_t)i*CONVDIM*4,
                                                           conv_b + (size_t)i*CONVDIM, xbc);
      dim3 gs(CB,3);
      scan_bf_kernel<<<gs,256,0,stream>>>(xbc, dt, A_log + (size_t)i*NHEADS, Dp + (size_t)i*NHEADS, y);
      gate_rms_bf_kernel<<<Mc,256,0,stream>>>(z, mnw + (size_t)i*DINNER, y);
      dim3 g2(DMODEL/128, Mc/128);
      gemm_bf16<1><<<g2,256,0,stream>>>(y, wbfout, DINNER, nullptr, nullptr, nullptr, nullptr, xc);
    }
  }
  final_kernel<<<BATCH,64,0,stream>>>(x, onw, onb, pw, pb, out);
}

// Round 5
// 1132.738 us; speedup vs baseline: 3.6130x; 1.3312x over previous
//
#include <hip/hip_runtime.h>
#include <math.h>

#define BATCH   256
#define SEQ     128
#define DMODEL  384
#define DSTATE  64
#define DINNER  768
#define NHEADS  12
#define HEADDIM 64
#define CONVDIM 896
#define DPROJ   1676
#define N1PAD   1792
#define OUTDIM  60
#define MTOT    (BATCH*SEQ)   // 32768

typedef unsigned short u16;
typedef short bf16x8 __attribute__((ext_vector_type(8)));
typedef float f32x4 __attribute__((ext_vector_type(4)));

#define ASG __attribute__((address_space(1)))
#define ASL __attribute__((address_space(3)))

__device__ __forceinline__ float siluf(float x){ return x / (1.f + expf(-x)); }
__device__ __forceinline__ float softplusf(float x){ return fmaxf(x,0.f) + log1pf(expf(-fabsf(x))); }
__device__ __forceinline__ u16 f2bf(float x){
  union { float f; unsigned int u; } c; c.f = x;
  unsigned int r = c.u + 0x7FFFu + ((c.u >> 16) & 1u);
  return (u16)(r >> 16);
}
__device__ __forceinline__ float bf2f(u16 u){
  union { unsigned int u; float f; } c; c.u = ((unsigned int)u) << 16;
  return c.f;
}

// x = emb + positional encoding
__global__ void add_pe_kernel(const float* __restrict__ emb, float* __restrict__ x){
  int idx = blockIdx.x*256 + threadIdx.x;
  int d = idx % DMODEL;
  int l = (idx / DMODEL) % SEQ;
  int i = d >> 1;
  float div = expf((float)(2*i) * (-9.210340371976184f/384.f));
  float arg = (float)l * div;
  float pe = (d & 1) ? cosf(arg) : sinf(arg);
  x[idx] = emb[idx] + pe;
}

// weight conversions (per layer, each call)
__global__ void wconv_in2_kernel(const float* __restrict__ w, u16* __restrict__ o){
  int idx = blockIdx.x*256 + threadIdx.x;       // N1PAD*DMODEL total
  int n = idx / DMODEL, k = idx % DMODEL;
  o[idx] = (n < DPROJ) ? f2bf(w[(size_t)n*DMODEL + k]) : (u16)0;
}
__global__ void wconv_out_kernel(const float* __restrict__ w, u16* __restrict__ o){
  int idx = blockIdx.x*256 + threadIdx.x;       // 384*768 total
  o[idx] = f2bf(w[idx]);
}

// xbf = bf16( LN(x)*lnw + lnb ), one wave per row
__global__ void __launch_bounds__(256) ln_bf_kernel(const float* __restrict__ x,
    const float* __restrict__ lnw, const float* __restrict__ lnb, u16* __restrict__ xbf){
  int wave = threadIdx.x >> 6, lane = threadIdx.x & 63;
  int m = blockIdx.x*4 + wave;
  const float* row = x + (size_t)m*DMODEL;
  float v[6], s=0.f, s2=0.f;
  #pragma unroll
  for (int j=0;j<6;j++){ v[j] = row[lane + 64*j]; s += v[j]; s2 += v[j]*v[j]; }
  #pragma unroll
  for (int off=32;off;off>>=1){ s += __shfl_xor(s,off,64); s2 += __shfl_xor(s2,off,64); }
  float m1 = s * (1.f/384.f);
  float var = s2 * (1.f/384.f) - m1*m1;
  float rstd = rsqrtf(var + 1e-5f);
  u16* orow = xbf + (size_t)m*DMODEL;
  #pragma unroll
  for (int j=0;j<6;j++){
    int d = lane + 64*j;
    orow[d] = f2bf((v[j]-m1)*rstd*lnw[d] + lnb[d]);
  }
}

// bf16 MFMA GEMM: C[m,n] = sum_k A[m,k]*W[n,k]; 128x128 tile, BK=64, 4 waves.
// MODE 0: in-proj epilogue (split z/xBCraw/dt);  MODE 1: out-proj (+= residual f32)
template<int MODE>
__global__ void __launch_bounds__(256) gemm_bf16(
    const u16* __restrict__ A, const u16* __restrict__ W, const int K,
    u16* __restrict__ zo, u16* __restrict__ xbcro, float* __restrict__ dto,
    const float* __restrict__ dt_bias, float* __restrict__ xres)
{
  __shared__ __align__(16) u16 As[128*64];
  __shared__ __align__(16) u16 Bs[128*64];
  const int tid = threadIdx.x;
  const int l = tid & 63;
  const int w = tid >> 6;
  const int wm = w >> 1, wn = w & 1;
  const int m0 = blockIdx.y * 128, n0 = blockIdx.x * 128;

  f32x4 acc[4][4];
  #pragma unroll
  for (int i=0;i<4;i++)
    #pragma unroll
    for (int j=0;j<4;j++)
      acc[i][j] = (f32x4){0.f,0.f,0.f,0.f};

  const int grow = tid >> 3;            // 0..31
  const int gcol = (tid & 7) * 8;
  const u16* Abase = A + (size_t)(m0 + grow)*K + gcol;
  const u16* Wbase = W + (size_t)(n0 + grow)*K + gcol;
  u16* asb = &As[w*512];                // wave-uniform LDS bases (lane*16B added by HW)
  u16* bsb = &Bs[w*512];

  for (int k0 = 0; k0 < K; k0 += 64){
    #pragma unroll
    for (int i=0;i<4;i++){
      __builtin_amdgcn_global_load_lds((const ASG void*)(Abase + (size_t)i*32*K + k0),
                                       (ASL void*)(asb + i*2048), 16, 0, 0);
      __builtin_amdgcn_global_load_lds((const ASG void*)(Wbase + (size_t)i*32*K + k0),
                                       (ASL void*)(bsb + i*2048), 16, 0, 0);
    }
    __syncthreads();
    #pragma unroll
    for (int ks=0; ks<64; ks+=32){
      const int ko = ks + ((l>>4)<<3);
      const int rr = l & 15;
      bf16x8 af[4], bfv[4];
      #pragma unroll
      for (int f=0; f<4; f++){
        af[f]  = *(const bf16x8*)&As[(wm*64 + f*16 + rr)*64 + ko];
        bfv[f] = *(const bf16x8*)&Bs[(wn*64 + f*16 + rr)*64 + ko];
      }
      #pragma unroll
      for (int fi=0; fi<4; fi++)
        #pragma unroll
        for (int fj=0; fj<4; fj++)
          acc[fi][fj] = __builtin_amdgcn_mfma_f32_16x16x32_bf16(af[fi], bfv[fj], acc[fi][fj], 0, 0, 0);
    }
    __syncthreads();
  }

  const int cg = l & 15;
  const int rb = (l >> 4) * 4;
  #pragma unroll
  for (int fi=0; fi<4; fi++){
    #pragma unroll
    for (int r=0; r<4; r++){
      const int m = m0 + wm*64 + fi*16 + rb + r;
      #pragma unroll
      for (int fj=0; fj<4; fj++){
        const int n = n0 + wn*64 + fj*16 + cg;
        float v = acc[fi][fj][r];
        if (MODE == 0){
          if (n < DINNER)            zo[(size_t)m*DINNER + n] = f2bf(v);
          else if (n < DINNER+CONVDIM) xbcro[(size_t)m*CONVDIM + n - DINNER] = f2bf(v);
          else if (n < DPROJ)        dto[(size_t)m*NHEADS + n - (DINNER+CONVDIM)] =
                                        softplusf(v + dt_bias[n - (DINNER+CONVDIM)]);
        } else {
          xres[(size_t)m*DMODEL + n] += v;
        }
      }
    }
  }
}

// Fused conv(width4)+SiLU+SSM scan. Block = (batch, head), 4 waves.
// Wave w owns states n in [16w,16w+16); lane = p (HEADDIM).
// Threads 0..127 additionally run the conv for the B/C channels and stage
// them in double-buffered LDS. Per-step: 2 barriers; partial y reduced in LDS.
__global__ void __launch_bounds__(256) scan_fused_kernel(
  const u16* __restrict__ xbcr, const float* __restrict__ dtb,
  const float* __restrict__ cw, const float* __restrict__ cb,
  const float* __restrict__ A_log, const float* __restrict__ Dp,
  u16* __restrict__ y)
{
  const int b   = blockIdx.x;           // chunk-local batch
  const int h   = blockIdx.y;           // 0..11
  const int tid = threadIdx.x;
  const int w   = tid >> 6;
  const int lane = tid & 63;
  const float A  = -expf(A_log[h]);
  const float Dh = Dp[h];

  // conv params: x channel (this head, this lane)
  const int cx = h*HEADDIM + lane;
  const float4 cwx = *(const float4*)&cw[cx*4];
  const float cbx = cb[cx];
  // conv params: B/C channel for tid<128
  float4 cwb = make_float4(0.f,0.f,0.f,0.f);
  float cbb = 0.f;
  if (tid < 128){
    cwb = *(const float4*)&cw[(DINNER + tid)*4];
    cbb = cb[DINNER + tid];
  }
  float hx1=0.f,hx2=0.f,hx3=0.f;        // raw x history (t-1,t-2,t-3)
  float hb1=0.f,hb2=0.f,hb3=0.f;        // raw B/C history
  float hs[16];
  #pragma unroll
  for (int j=0;j<16;j++) hs[j]=0.f;

  __shared__ float bc[2][128];
  __shared__ float part[256];

  const u16* xb   = xbcr + (size_t)b*SEQ*CONVDIM;
  const float* dr = dtb  + (size_t)b*SEQ*NHEADS;
  u16* yb = y + (size_t)b*SEQ*DINNER;
  const int n0 = w*16;

  for (int t=0; t<SEQ; t++){
    const float rawx = bf2f(xb[t*CONVDIM + cx]);
    const float dtv  = dr[t*NHEADS + h];
    const float xval = siluf(cbx + hx3*cwx.x + hx2*cwx.y + hx1*cwx.z + rawx*cwx.w);
    hx3=hx2; hx2=hx1; hx1=rawx;
    if (tid < 128){
      const float rawb = bf2f(xb[t*CONVDIM + DINNER + tid]);
      bc[t&1][tid] = siluf(cbb + hb3*cwb.x + hb2*cwb.y + hb1*cwb.z + rawb*cwb.w);
      hb3=hb2; hb2=hb1; hb1=rawb;
    }
    __syncthreads();                    // bc[t&1] ready; part[] free to rewrite
    const float dA   = expf(dtv*A);
    const float coef = dtv*xval;
    const float* bcb = bc[t&1];
    float yacc = 0.f;
    #pragma unroll
    for (int q=0;q<4;q++){
      float4 B4 = *(const float4*)&bcb[n0 + 4*q];
      float4 C4 = *(const float4*)&bcb[64 + n0 + 4*q];
      hs[4*q+0] = fmaf(hs[4*q+0], dA, coef*B4.x); yacc = fmaf(hs[4*q+0], C4.x, yacc);
      hs[4*q+1] = fmaf(hs[4*q+1], dA, coef*B4.y); yacc = fmaf(hs[4*q+1], C4.y, yacc);
      hs[4*q+2] = fmaf(hs[4*q+2], dA, coef*B4.z); yacc = fmaf(hs[4*q+2], C4.z, yacc);
      hs[4*q+3] = fmaf(hs[4*q+3], dA, coef*B4.w); yacc = fmaf(hs[4*q+3], C4.w, yacc);
    }
    part[tid] = yacc;
    __syncthreads();                    // partials ready
    if (w == 0){
      float tot = part[lane] + part[64+lane] + part[128+lane] + part[192+lane];
      yb[t*DINNER + h*HEADDIM + lane] = f2bf(tot + Dh*xval);
    }
  }
}

// g = y * silu(z); g *= rsqrt(mean(g^2)+eps) * norm_w  (bf16 in-place in y)
__global__ void __launch_bounds__(256) gate_rms_bf_kernel(const u16* __restrict__ z,
    const float* __restrict__ normw, u16* __restrict__ y){
  int m = blockIdx.x;
  int tid = threadIdx.x;
  float g[3];
  float ss = 0.f;
  const u16* zrow = z + (size_t)m*DINNER;
  u16* yrow = y + (size_t)m*DINNER;
  #pragma unroll
  for (int j=0;j<3;j++){
    int e = tid + 256*j;
    float zv = bf2f(zrow[e]);
    float gv = bf2f(yrow[e]) * siluf(zv);
    g[j] = gv;
    ss += gv*gv;
  }
  #pragma unroll
  for (int off=32;off;off>>=1) ss += __shfl_xor(ss,off,64);
  __shared__ float red[4];
  if ((tid&63)==0) red[tid>>6] = ss;
  __syncthreads();
  float tot = red[0]+red[1]+red[2]+red[3];
  float rms = rsqrtf(tot*(1.f/768.f) + 1e-5f);
  #pragma unroll
  for (int j=0;j<3;j++){
    int e = tid + 256*j;
    yrow[e] = f2bf(g[j]*rms*normw[e]);
  }
}

// final LN on last timestep + 60x384 projection (f32)
__global__ void __launch_bounds__(64) final_kernel(const float* __restrict__ x,
  const float* __restrict__ onw, const float* __restrict__ onb,
  const float* __restrict__ pw, const float* __restrict__ pb, float* __restrict__ out)
{
  int b = blockIdx.x;
  int lane = threadIdx.x;
  const float* row = x + ((size_t)b*SEQ + (SEQ-1))*DMODEL;
  float s=0.f, s2=0.f;
  float v[6];
  #pragma unroll
  for (int j=0;j<6;j++){ v[j] = row[lane + 64*j]; s += v[j]; s2 += v[j]*v[j]; }
  #pragma unroll
  for (int off=32;off;off>>=1){ s += __shfl_xor(s,off,64); s2 += __shfl_xor(s2,off,64); }
  float m1 = s*(1.f/384.f);
  float var = s2*(1.f/384.f) - m1*m1;
  float rstd = rsqrtf(var + 1e-5f);
  __shared__ float xn[384];
  #pragma unroll
  for (int j=0;j<6;j++){
    int d = lane + 64*j;
    xn[d] = (v[j]-m1)*rstd*onw[d] + onb[d];
  }
  __syncthreads();
  if (lane < OUTDIM){
    const float* wrow = pw + lane*DMODEL;
    float acc = pb[lane];
    #pragma unroll 4
    for (int d=0; d<DMODEL; d+=4){
      float4 xv = *(const float4*)&xn[d];
      float4 wv = *(const float4*)&wrow[d];
      acc += xv.x*wv.x + xv.y*wv.y + xv.z*wv.z + xv.w*wv.w;
    }
    out[b*OUTDIM + lane] = acc;
  }
}

extern "C" void kernel_launch(void* const* d_in, const int* in_sizes, int n_in,
                              void* d_out, int out_size, void* d_ws, size_t ws_size,
                              hipStream_t stream){
  const float* emb        = (const float*)d_in[0];
  const float* in_proj_w  = (const float*)d_in[1];
  const float* conv_w     = (const float*)d_in[2];
  const float* conv_b     = (const float*)d_in[3];
  const float* dt_bias    = (const float*)d_in[4];
  const float* A_log      = (const float*)d_in[5];
  const float* Dp         = (const float*)d_in[6];
  const float* mnw        = (const float*)d_in[7];
  const float* out_proj_w = (const float*)d_in[8];
  const float* ln_w       = (const float*)d_in[9];
  const float* ln_b       = (const float*)d_in[10];
  const float* onw        = (const float*)d_in[11];
  const float* onb        = (const float*)d_in[12];
  const float* pw         = (const float*)d_in[13];
  const float* pb         = (const float*)d_in[14];
  float* out = (float*)d_out;

  // ---- adaptive workspace ----
  // fixed: x f32 (50.33MB), xbf bf16 (25.17MB), wbf_in (1.38MB), wbf_out (0.59MB)
  // per row (chunked): z 1536 + xbcr 1792 + dt 48 + y 1536 = 4912 B
  const size_t XB    = (size_t)MTOT*DMODEL*4;
  const size_t XBFB  = (size_t)MTOT*DMODEL*2;
  const size_t WINB  = (size_t)N1PAD*DMODEL*2;
  const size_t WOUTB = (size_t)DMODEL*DINNER*2;
  const size_t fixed = XB + XBFB + WINB + WOUTB;
  int CB = 256;
  while (CB > 1 && fixed + (size_t)CB*SEQ*4912ull > ws_size) CB >>= 1;
  const int Mc = CB*SEQ;
  const int nchunks = BATCH / CB;

  char* p = (char*)d_ws;
  float* x      = (float*)p;  p += XB;
  u16*   xbf    = (u16*)p;    p += XBFB;
  u16*   wbfin  = (u16*)p;    p += WINB;
  u16*   wbfout = (u16*)p;    p += WOUTB;
  u16*   z      = (u16*)p;    p += (size_t)Mc*DINNER*2;
  u16*   xbcr   = (u16*)p;    p += (size_t)Mc*CONVDIM*2;
  float* dt     = (float*)p;  p += (size_t)Mc*NHEADS*4;
  u16*   y      = (u16*)p;

  add_pe_kernel<<<MTOT*DMODEL/256,256,0,stream>>>(emb, x);
  for (int i=0;i<2;i++){
    wconv_in2_kernel<<<N1PAD*DMODEL/256,256,0,stream>>>(in_proj_w + (size_t)i*DPROJ*DMODEL, wbfin);
    wconv_out_kernel<<<DMODEL*DINNER/256,256,0,stream>>>(out_proj_w + (size_t)i*DMODEL*DINNER, wbfout);
    ln_bf_kernel<<<MTOT/4,256,0,stream>>>(x, ln_w + (size_t)i*DMODEL, ln_b + (size_t)i*DMODEL, xbf);
    for (int c=0;c<nchunks;c++){
      const u16* ac = xbf + (size_t)c*Mc*DMODEL;
      float*     xc = x   + (size_t)c*Mc*DMODEL;
      dim3 g1(N1PAD/128, Mc/128);
      gemm_bf16<0><<<g1,256,0,stream>>>(ac, wbfin, DMODEL, z, xbcr, dt,
                                        dt_bias + (size_t)i*NHEADS, nullptr);
      dim3 gs(CB, NHEADS);
      scan_fused_kernel<<<gs,256,0,stream>>>(xbcr, dt,
          conv_w + (size_t)i*CONVDIM*4, conv_b + (size_t)i*CONVDIM,
          A_log + (size_t)i*NHEADS, Dp + (size_t)i*NHEADS, y);
      gate_rms_bf_kernel<<<Mc,256,0,stream>>>(z, mnw + (size_t)i*DINNER, y);
      dim3 g2(DMODEL/128, Mc/128);
      gemm_bf16<1><<<g2,256,0,stream>>>(y, wbfout, DINNER, nullptr, nullptr, nullptr, nullptr, xc);
    }
  }
  final_kernel<<<BATCH,64,0,stream>>>(x, onw, onb, pw, pb, out);
}

// Round 6
// 934.394 us; speedup vs baseline: 4.3799x; 1.2123x over previous
//
#include <hip/hip_runtime.h>
#include <math.h>

#define BATCH   256
#define SEQ     128
#define DMODEL  384
#define DSTATE  64
#define DINNER  768
#define NHEADS  12
#define HEADDIM 64
#define CONVDIM 896
#define DPROJ   1676
#define N1PAD   1792
#define OUTDIM  60
#define MTOT    (BATCH*SEQ)   // 32768

typedef unsigned short u16;
typedef unsigned int   u32;
typedef short bf16x8 __attribute__((ext_vector_type(8)));
typedef float f32x4 __attribute__((ext_vector_type(4)));

#define ASG __attribute__((address_space(1)))
#define ASL __attribute__((address_space(3)))

__device__ __forceinline__ float siluf(float x){ return x / (1.f + expf(-x)); }
__device__ __forceinline__ float softplusf(float x){ return fmaxf(x,0.f) + log1pf(expf(-fabsf(x))); }
__device__ __forceinline__ u16 f2bf(float x){
  union { float f; unsigned int u; } c; c.f = x;
  unsigned int r = c.u + 0x7FFFu + ((c.u >> 16) & 1u);
  return (u16)(r >> 16);
}
__device__ __forceinline__ float bf2f(u16 u){
  union { unsigned int u; float f; } c; c.u = ((unsigned int)u) << 16;
  return c.f;
}

// x = emb + positional encoding
__global__ void add_pe_kernel(const float* __restrict__ emb, float* __restrict__ x){
  int idx = blockIdx.x*256 + threadIdx.x;
  int d = idx % DMODEL;
  int l = (idx / DMODEL) % SEQ;
  int i = d >> 1;
  float div = expf((float)(2*i) * (-9.210340371976184f/384.f));
  float arg = (float)l * div;
  float pe = (d & 1) ? cosf(arg) : sinf(arg);
  x[idx] = emb[idx] + pe;
}

// weight conversions (per layer, each call)
__global__ void wconv_in2_kernel(const float* __restrict__ w, u16* __restrict__ o){
  int idx = blockIdx.x*256 + threadIdx.x;       // N1PAD*DMODEL total
  int n = idx / DMODEL, k = idx % DMODEL;
  o[idx] = (n < DPROJ) ? f2bf(w[(size_t)n*DMODEL + k]) : (u16)0;
}
__global__ void wconv_out_kernel(const float* __restrict__ w, u16* __restrict__ o){
  int idx = blockIdx.x*256 + threadIdx.x;       // 384*768 total
  o[idx] = f2bf(w[idx]);
}

// xbf = bf16( LN(x)*lnw + lnb ), one wave per row
__global__ void __launch_bounds__(256) ln_bf_kernel(const float* __restrict__ x,
    const float* __restrict__ lnw, const float* __restrict__ lnb, u16* __restrict__ xbf){
  int wave = threadIdx.x >> 6, lane = threadIdx.x & 63;
  int m = blockIdx.x*4 + wave;
  const float* row = x + (size_t)m*DMODEL;
  float v[6], s=0.f, s2=0.f;
  #pragma unroll
  for (int j=0;j<6;j++){ v[j] = row[lane + 64*j]; s += v[j]; s2 += v[j]*v[j]; }
  #pragma unroll
  for (int off=32;off;off>>=1){ s += __shfl_xor(s,off,64); s2 += __shfl_xor(s2,off,64); }
  float m1 = s * (1.f/384.f);
  float var = s2 * (1.f/384.f) - m1*m1;
  float rstd = rsqrtf(var + 1e-5f);
  u16* orow = xbf + (size_t)m*DMODEL;
  #pragma unroll
  for (int j=0;j<6;j++){
    int d = lane + 64*j;
    orow[d] = f2bf((v[j]-m1)*rstd*lnw[d] + lnb[d]);
  }
}

// bf16 MFMA GEMM: C[m,n] = sum_k A[m,k]*W[n,k]; 128x128 tile, BK=64, 4 waves.
// MODE 0: in-proj epilogue (split z/xBCraw/dt);  MODE 1: out-proj (+= residual f32)
template<int MODE>
__global__ void __launch_bounds__(256) gemm_bf16(
    const u16* __restrict__ A, const u16* __restrict__ W, const int K,
    u16* __restrict__ zo, u16* __restrict__ xbcro, float* __restrict__ dto,
    const float* __restrict__ dt_bias, float* __restrict__ xres)
{
  __shared__ __align__(16) u16 As[128*64];
  __shared__ __align__(16) u16 Bs[128*64];
  const int tid = threadIdx.x;
  const int l = tid & 63;
  const int w = tid >> 6;
  const int wm = w >> 1, wn = w & 1;
  const int m0 = blockIdx.y * 128, n0 = blockIdx.x * 128;

  f32x4 acc[4][4];
  #pragma unroll
  for (int i=0;i<4;i++)
    #pragma unroll
    for (int j=0;j<4;j++)
      acc[i][j] = (f32x4){0.f,0.f,0.f,0.f};

  const int grow = tid >> 3;            // 0..31
  const int gcol = (tid & 7) * 8;
  const u16* Abase = A + (size_t)(m0 + grow)*K + gcol;
  const u16* Wbase = W + (size_t)(n0 + grow)*K + gcol;
  u16* asb = &As[w*512];                // wave-uniform LDS bases (lane*16B added by HW)
  u16* bsb = &Bs[w*512];

  for (int k0 = 0; k0 < K; k0 += 64){
    #pragma unroll
    for (int i=0;i<4;i++){
      __builtin_amdgcn_global_load_lds((const ASG void*)(Abase + (size_t)i*32*K + k0),
                                       (ASL void*)(asb + i*2048), 16, 0, 0);
      __builtin_amdgcn_global_load_lds((const ASG void*)(Wbase + (size_t)i*32*K + k0),
                                       (ASL void*)(bsb + i*2048), 16, 0, 0);
    }
    __syncthreads();
    #pragma unroll
    for (int ks=0; ks<64; ks+=32){
      const int ko = ks + ((l>>4)<<3);
      const int rr = l & 15;
      bf16x8 af[4], bfv[4];
      #pragma unroll
      for (int f=0; f<4; f++){
        af[f]  = *(const bf16x8*)&As[(wm*64 + f*16 + rr)*64 + ko];
        bfv[f] = *(const bf16x8*)&Bs[(wn*64 + f*16 + rr)*64 + ko];
      }
      #pragma unroll
      for (int fi=0; fi<4; fi++)
        #pragma unroll
        for (int fj=0; fj<4; fj++)
          acc[fi][fj] = __builtin_amdgcn_mfma_f32_16x16x32_bf16(af[fi], bfv[fj], acc[fi][fj], 0, 0, 0);
    }
    __syncthreads();
  }

  const int cg = l & 15;
  const int rb = (l >> 4) * 4;
  #pragma unroll
  for (int fi=0; fi<4; fi++){
    #pragma unroll
    for (int r=0; r<4; r++){
      const int m = m0 + wm*64 + fi*16 + rb + r;
      #pragma unroll
      for (int fj=0; fj<4; fj++){
        const int n = n0 + wn*64 + fj*16 + cg;
        float v = acc[fi][fj][r];
        if (MODE == 0){
          if (n < DINNER)            zo[(size_t)m*DINNER + n] = f2bf(v);
          else if (n < DINNER+CONVDIM) xbcro[(size_t)m*CONVDIM + n - DINNER] = f2bf(v);
          else if (n < DPROJ)        dto[(size_t)m*NHEADS + n - (DINNER+CONVDIM)] =
                                        softplusf(v + dt_bias[n - (DINNER+CONVDIM)]);
        } else {
          xres[(size_t)m*DMODEL + n] += v;
        }
      }
    }
  }
}

// depthwise causal conv (width 4) + bias + SiLU, bf16 in/out
__global__ void conv_silu_bf_kernel(const u16* __restrict__ xbcr, const float* __restrict__ cw,
                                    const float* __restrict__ cb, u16* __restrict__ xbc){
  int idx = blockIdx.x*256 + threadIdx.x;   // Mc*CONVDIM total
  int c = idx % CONVDIM;
  int lm = idx / CONVDIM;
  int lq = lm % SEQ;
  float acc = cb[c];
  const float* wc = cw + c*4;
  const u16* col = xbcr + (size_t)lm*CONVDIM + c;
  #pragma unroll
  for (int k=0;k<4;k++){
    int dl = k - 3;
    if (lq + dl >= 0)
      acc = fmaf(bf2f(col[(long)dl*CONVDIM]), wc[k], acc);
  }
  xbc[idx] = f2bf(siluf(acc));
}

// SSD (Mamba2 matrix form) for one (batch, head): SEQ=128 single chunk.
// G = C·B^T (MFMA), M[t,s] = [t>=s]·exp(cum[t]-cum[s])·dt[s]·G[t,s] (bf16),
// Y = M·X (MFMA), y = Y + D·x. 4 waves, wave w owns t in [32w, 32w+32).
__global__ void __launch_bounds__(256) ssd_kernel(
  const u16* __restrict__ xbc, const float* __restrict__ dtb,
  const float* __restrict__ A_log, const float* __restrict__ Dp,
  u16* __restrict__ y)
{
  const int b = blockIdx.x, h = blockIdx.y;
  const int tid = threadIdx.x;
  const int l = tid & 63;
  const int w = tid >> 6;
  const float A  = -expf(A_log[h]);
  const float Dh = Dp[h];

  // LDS: C/B staged at stride 72 u16 (144B, 16B-aligned, 2-way banks);
  // M (128x136 u16) reuses the C+B region after G completes.
  __shared__ __align__(16) u16 cbm[2*128*72];       // 36864 B
  __shared__ __align__(16) u16 XtS[64*136];         // 17408 B, Xt[p][s]
  __shared__ float cum[128];
  __shared__ float dts[128];
  u16* Cs = cbm;                 // [128][72]
  u16* Bq = cbm + 128*72;        // [128][72]
  u16* Ms = cbm;                 // [128][136]

  const u16* xrow = xbc + (size_t)b*SEQ*CONVDIM;

  // stage B (cols 768..832) and C (cols 832..896), 16B per thread per iter
  {
    const int row0 = tid >> 3;         // 0..31
    const int col  = (tid & 7) * 8;
    #pragma unroll
    for (int it=0; it<4; it++){
      const int row = row0 + 32*it;
      *(bf16x8*)&Bq[row*72 + col] = *(const bf16x8*)&xrow[(size_t)row*CONVDIM + DINNER + col];
      *(bf16x8*)&Cs[row*72 + col] = *(const bf16x8*)&xrow[(size_t)row*CONVDIM + DINNER + DSTATE + col];
    }
  }
  // stage X transposed: Xt[p][s] = x[s][h*64+p]; two s-rows -> one b32 write
  {
    #pragma unroll
    for (int it=0; it<16; it++){
      const int sp = (tid>>6) + 4*it;       // 0..63
      const int s  = 2*sp;
      u32 lo = xrow[(size_t)s*CONVDIM + h*HEADDIM + l];
      u32 hi = xrow[(size_t)(s+1)*CONVDIM + h*HEADDIM + l];
      *(u32*)&XtS[l*136 + s] = lo | (hi << 16);
    }
  }
  // dt + inclusive cumsum of dt*A (Hillis-Steele)
  if (tid < 128){
    float a = dtb[((size_t)b*SEQ + tid)*NHEADS + h];
    dts[tid] = a;
    cum[tid] = a * A;
  }
  __syncthreads();
  for (int off=1; off<128; off<<=1){
    float v = 0.f;
    if (tid < 128 && tid >= off) v = cum[tid-off];
    __syncthreads();
    if (tid < 128) cum[tid] += v;
    __syncthreads();
  }

  // ---- G = C · B^T : wave computes rows [32w, 32w+32) x all 128 cols ----
  const int t0 = w*32;
  const int rr = l & 15;
  f32x4 g[2][8];
  #pragma unroll
  for (int i=0;i<2;i++)
    #pragma unroll
    for (int j=0;j<8;j++)
      g[i][j] = (f32x4){0.f,0.f,0.f,0.f};
  #pragma unroll
  for (int k0=0; k0<64; k0+=32){
    const int ko = k0 + ((l>>4)<<3);
    bf16x8 af[2], bfv[8];
    #pragma unroll
    for (int fi=0; fi<2; fi++) af[fi]  = *(const bf16x8*)&Cs[(t0 + 16*fi + rr)*72 + ko];
    #pragma unroll
    for (int fj=0; fj<8; fj++) bfv[fj] = *(const bf16x8*)&Bq[(16*fj + rr)*72 + ko];
    #pragma unroll
    for (int fi=0; fi<2; fi++)
      #pragma unroll
      for (int fj=0; fj<8; fj++)
        g[fi][fj] = __builtin_amdgcn_mfma_f32_16x16x32_bf16(af[fi], bfv[fj], g[fi][fj], 0, 0, 0);
  }
  __syncthreads();   // all C/B reads done; M may overwrite the region

  // ---- M[t,s] = mask * exp(cum[t]-cum[s]) * dt[s] * G ----
  {
    const int rowg = (l >> 4) * 4;
    const int colg = l & 15;
    #pragma unroll
    for (int fi=0; fi<2; fi++){
      #pragma unroll
      for (int fj=0; fj<8; fj++){
        const int s = 16*fj + colg;
        const float cs = cum[s];
        const float ds = dts[s];
        #pragma unroll
        for (int r=0; r<4; r++){
          const int t = t0 + 16*fi + rowg + r;
          float m = 0.f;
          if (t >= s) m = expf(cum[t] - cs) * ds * g[fi][fj][r];
          Ms[t*136 + s] = f2bf(m);
        }
      }
    }
  }
  __syncthreads();   // M visible (and ordered) for fragment reads

  // ---- Y = M · X : rows [32w,32w+32) x 64, K = 128 ----
  f32x4 acc[2][4];
  #pragma unroll
  for (int i=0;i<2;i++)
    #pragma unroll
    for (int j=0;j<4;j++)
      acc[i][j] = (f32x4){0.f,0.f,0.f,0.f};
  #pragma unroll
  for (int k0=0; k0<128; k0+=32){
    const int ko = k0 + ((l>>4)<<3);
    bf16x8 af[2], bfv[4];
    #pragma unroll
    for (int fi=0; fi<2; fi++) af[fi]  = *(const bf16x8*)&Ms[(t0 + 16*fi + rr)*136 + ko];
    #pragma unroll
    for (int fj=0; fj<4; fj++) bfv[fj] = *(const bf16x8*)&XtS[(16*fj + rr)*136 + ko];
    #pragma unroll
    for (int fi=0; fi<2; fi++)
      #pragma unroll
      for (int fj=0; fj<4; fj++)
        acc[fi][fj] = __builtin_amdgcn_mfma_f32_16x16x32_bf16(af[fi], bfv[fj], acc[fi][fj], 0, 0, 0);
  }

  // ---- epilogue: y = Y + D*x ----
  {
    const int rowg = (l >> 4) * 4;
    const int colg = l & 15;
    u16* yb = y + (size_t)b*SEQ*DINNER + h*HEADDIM;
    #pragma unroll
    for (int fi=0; fi<2; fi++){
      #pragma unroll
      for (int r=0; r<4; r++){
        const int t = t0 + 16*fi + rowg + r;
        #pragma unroll
        for (int fj=0; fj<4; fj++){
          const int p = 16*fj + colg;
          const float xval = bf2f(xrow[(size_t)t*CONVDIM + h*HEADDIM + p]);
          yb[(size_t)t*DINNER + p] = f2bf(acc[fi][fj][r] + Dh*xval);
        }
      }
    }
  }
}

// g = y * silu(z); g *= rsqrt(mean(g^2)+eps) * norm_w  (bf16 in-place in y)
__global__ void __launch_bounds__(256) gate_rms_bf_kernel(const u16* __restrict__ z,
    const float* __restrict__ normw, u16* __restrict__ y){
  int m = blockIdx.x;
  int tid = threadIdx.x;
  float g[3];
  float ss = 0.f;
  const u16* zrow = z + (size_t)m*DINNER;
  u16* yrow = y + (size_t)m*DINNER;
  #pragma unroll
  for (int j=0;j<3;j++){
    int e = tid + 256*j;
    float zv = bf2f(zrow[e]);
    float gv = bf2f(yrow[e]) * siluf(zv);
    g[j] = gv;
    ss += gv*gv;
  }
  #pragma unroll
  for (int off=32;off;off>>=1) ss += __shfl_xor(ss,off,64);
  __shared__ float red[4];
  if ((tid&63)==0) red[tid>>6] = ss;
  __syncthreads();
  float tot = red[0]+red[1]+red[2]+red[3];
  float rms = rsqrtf(tot*(1.f/768.f) + 1e-5f);
  #pragma unroll
  for (int j=0;j<3;j++){
    int e = tid + 256*j;
    yrow[e] = f2bf(g[j]*rms*normw[e]);
  }
}

// final LN on last timestep + 60x384 projection (f32)
__global__ void __launch_bounds__(64) final_kernel(const float* __restrict__ x,
  const float* __restrict__ onw, const float* __restrict__ onb,
  const float* __restrict__ pw, const float* __restrict__ pb, float* __restrict__ out)
{
  int b = blockIdx.x;
  int lane = threadIdx.x;
  const float* row = x + ((size_t)b*SEQ + (SEQ-1))*DMODEL;
  float s=0.f, s2=0.f;
  float v[6];
  #pragma unroll
  for (int j=0;j<6;j++){ v[j] = row[lane + 64*j]; s += v[j]; s2 += v[j]*v[j]; }
  #pragma unroll
  for (int off=32;off;off>>=1){ s += __shfl_xor(s,off,64); s2 += __shfl_xor(s2,off,64); }
  float m1 = s*(1.f/384.f);
  float var = s2*(1.f/384.f) - m1*m1;
  float rstd = rsqrtf(var + 1e-5f);
  __shared__ float xn[384];
  #pragma unroll
  for (int j=0;j<6;j++){
    int d = lane + 64*j;
    xn[d] = (v[j]-m1)*rstd*onw[d] + onb[d];
  }
  __syncthreads();
  if (lane < OUTDIM){
    const float* wrow = pw + lane*DMODEL;
    float acc = pb[lane];
    #pragma unroll 4
    for (int d=0; d<DMODEL; d+=4){
      float4 xv = *(const float4*)&xn[d];
      float4 wv = *(const float4*)&wrow[d];
      acc += xv.x*wv.x + xv.y*wv.y + xv.z*wv.z + xv.w*wv.w;
    }
    out[b*OUTDIM + lane] = acc;
  }
}

extern "C" void kernel_launch(void* const* d_in, const int* in_sizes, int n_in,
                              void* d_out, int out_size, void* d_ws, size_t ws_size,
                              hipStream_t stream){
  const float* emb        = (const float*)d_in[0];
  const float* in_proj_w  = (const float*)d_in[1];
  const float* conv_w     = (const float*)d_in[2];
  const float* conv_b     = (const float*)d_in[3];
  const float* dt_bias    = (const float*)d_in[4];
  const float* A_log      = (const float*)d_in[5];
  const float* Dp         = (const float*)d_in[6];
  const float* mnw        = (const float*)d_in[7];
  const float* out_proj_w = (const float*)d_in[8];
  const float* ln_w       = (const float*)d_in[9];
  const float* ln_b       = (const float*)d_in[10];
  const float* onw        = (const float*)d_in[11];
  const float* onb        = (const float*)d_in[12];
  const float* pw         = (const float*)d_in[13];
  const float* pb         = (const float*)d_in[14];
  float* out = (float*)d_out;

  // ---- adaptive workspace ----
  // fixed: x f32, xbf bf16, wbf_in, wbf_out
  // per row (chunked): z 1536 + xbcr 1792 + xbc 1792 + dt 48 + y 1536 = 6704 B
  const size_t XB    = (size_t)MTOT*DMODEL*4;
  const size_t XBFB  = (size_t)MTOT*DMODEL*2;
  const size_t WINB  = (size_t)N1PAD*DMODEL*2;
  const size_t WOUTB = (size_t)DMODEL*DINNER*2;
  const size_t fixed = XB + XBFB + WINB + WOUTB;
  int CB = 256;
  while (CB > 1 && fixed + (size_t)CB*SEQ*6704ull > ws_size) CB >>= 1;
  const int Mc = CB*SEQ;
  const int nchunks = BATCH / CB;

  char* p = (char*)d_ws;
  float* x      = (float*)p;  p += XB;
  u16*   xbf    = (u16*)p;    p += XBFB;
  u16*   wbfin  = (u16*)p;    p += WINB;
  u16*   wbfout = (u16*)p;    p += WOUTB;
  u16*   z      = (u16*)p;    p += (size_t)Mc*DINNER*2;
  u16*   xbcr   = (u16*)p;    p += (size_t)Mc*CONVDIM*2;
  u16*   xbc    = (u16*)p;    p += (size_t)Mc*CONVDIM*2;
  float* dt     = (float*)p;  p += (size_t)Mc*NHEADS*4;
  u16*   y      = (u16*)p;

  add_pe_kernel<<<MTOT*DMODEL/256,256,0,stream>>>(emb, x);
  for (int i=0;i<2;i++){
    wconv_in2_kernel<<<N1PAD*DMODEL/256,256,0,stream>>>(in_proj_w + (size_t)i*DPROJ*DMODEL, wbfin);
    wconv_out_kernel<<<DMODEL*DINNER/256,256,0,stream>>>(out_proj_w + (size_t)i*DMODEL*DINNER, wbfout);
    ln_bf_kernel<<<MTOT/4,256,0,stream>>>(x, ln_w + (size_t)i*DMODEL, ln_b + (size_t)i*DMODEL, xbf);
    for (int c=0;c<nchunks;c++){
      const u16* ac = xbf + (size_t)c*Mc*DMODEL;
      float*     xc = x   + (size_t)c*Mc*DMODEL;
      dim3 g1(N1PAD/128, Mc/128);
      gemm_bf16<0><<<g1,256,0,stream>>>(ac, wbfin, DMODEL, z, xbcr, dt,
                                        dt_bias + (size_t)i*NHEADS, nullptr);
      conv_silu_bf_kernel<<<Mc*CONVDIM/256,256,0,stream>>>(xbcr, conv_w + (size_t)i*CONVDIM*4,
                                                           conv_b + (size_t)i*CONVDIM, xbc);
      dim3 gs(CB, NHEADS);
      ssd_kernel<<<gs,256,0,stream>>>(xbc, dt, A_log + (size_t)i*NHEADS, Dp + (size_t)i*NHEADS, y);
      gate_rms_bf_kernel<<<Mc,256,0,stream>>>(z, mnw + (size_t)i*DINNER, y);
      dim3 g2(DMODEL/128, Mc/128);
      gemm_bf16<1><<<g2,256,0,stream>>>(y, wbfout, DINNER, nullptr, nullptr, nullptr, nullptr, xc);
    }
  }
  final_kernel<<<BATCH,64,0,stream>>>(x, onw, onb, pw, pb, out);
}

// Round 7
// 680.755 us; speedup vs baseline: 6.0118x; 1.3726x over previous
//
#include <hip/hip_runtime.h>
#include <math.h>

#define BATCH   256
#define SEQ     128
#define DMODEL  384
#define DSTATE  64
#define DINNER  768
#define NHEADS  12
#define HEADDIM 64
#define CONVDIM 896
#define DPROJ   1676
#define N1PAD   1792
#define OUTDIM  60
#define MTOT    (BATCH*SEQ)   // 32768

typedef unsigned short u16;
typedef unsigned int   u32;
typedef short bf16x8 __attribute__((ext_vector_type(8)));
typedef float f32x4 __attribute__((ext_vector_type(4)));

#define ASG __attribute__((address_space(1)))
#define ASL __attribute__((address_space(3)))

__device__ __forceinline__ float siluf(float x){ return x / (1.f + expf(-x)); }
__device__ __forceinline__ float softplusf(float x){ return fmaxf(x,0.f) + log1pf(expf(-fabsf(x))); }
__device__ __forceinline__ u16 f2bf(float x){
  union { float f; unsigned int u; } c; c.f = x;
  unsigned int r = c.u + 0x7FFFu + ((c.u >> 16) & 1u);
  return (u16)(r >> 16);
}
__device__ __forceinline__ float bf2f(u16 u){
  union { unsigned int u; float f; } c; c.u = ((unsigned int)u) << 16;
  return c.f;
}

// x = emb + positional encoding
__global__ void add_pe_kernel(const float* __restrict__ emb, float* __restrict__ x){
  int idx = blockIdx.x*256 + threadIdx.x;
  int d = idx % DMODEL;
  int l = (idx / DMODEL) % SEQ;
  int i = d >> 1;
  float div = expf((float)(2*i) * (-9.210340371976184f/384.f));
  float arg = (float)l * div;
  float pe = (d & 1) ? cosf(arg) : sinf(arg);
  x[idx] = emb[idx] + pe;
}

// weight conversions (per layer, each call)
__global__ void wconv_in2_kernel(const float* __restrict__ w, u16* __restrict__ o){
  int idx = blockIdx.x*256 + threadIdx.x;       // N1PAD*DMODEL total
  int n = idx / DMODEL, k = idx % DMODEL;
  o[idx] = (n < DPROJ) ? f2bf(w[(size_t)n*DMODEL + k]) : (u16)0;
}
__global__ void wconv_out_kernel(const float* __restrict__ w, u16* __restrict__ o){
  int idx = blockIdx.x*256 + threadIdx.x;       // 384*768 total
  o[idx] = f2bf(w[idx]);
}

// xbf = bf16( LN(x)*lnw + lnb ), one wave per row
__global__ void __launch_bounds__(256) ln_bf_kernel(const float* __restrict__ x,
    const float* __restrict__ lnw, const float* __restrict__ lnb, u16* __restrict__ xbf){
  int wave = threadIdx.x >> 6, lane = threadIdx.x & 63;
  int m = blockIdx.x*4 + wave;
  const float* row = x + (size_t)m*DMODEL;
  float v[6], s=0.f, s2=0.f;
  #pragma unroll
  for (int j=0;j<6;j++){ v[j] = row[lane + 64*j]; s += v[j]; s2 += v[j]*v[j]; }
  #pragma unroll
  for (int off=32;off;off>>=1){ s += __shfl_xor(s,off,64); s2 += __shfl_xor(s2,off,64); }
  float m1 = s * (1.f/384.f);
  float var = s2 * (1.f/384.f) - m1*m1;
  float rstd = rsqrtf(var + 1e-5f);
  u16* orow = xbf + (size_t)m*DMODEL;
  #pragma unroll
  for (int j=0;j<6;j++){
    int d = lane + 64*j;
    orow[d] = f2bf((v[j]-m1)*rstd*lnw[d] + lnb[d]);
  }
}

// bf16 MFMA GEMM, 2-phase pipelined: 128x128 tile, BK=32, double-buffered LDS,
// STAGE(t+1) issued before compute(t); one barrier/iter (its implicit vmcnt(0)
// is the counted wait). XCD-aware block swizzle for A-panel L2 locality.
// MODE 0: in-proj epilogue (split z/xBCraw/dt);  MODE 1: out-proj (+= residual f32)
template<int MODE>
__global__ void __launch_bounds__(256) gemm_bf16(
    const u16* __restrict__ A, const u16* __restrict__ W, const int K,
    u16* __restrict__ zo, u16* __restrict__ xbcro, float* __restrict__ dto,
    const float* __restrict__ dt_bias, float* __restrict__ xres)
{
  __shared__ __align__(16) u16 As[2*128*32];
  __shared__ __align__(16) u16 Bs[2*128*32];
  const int tid = threadIdx.x;
  const int l = tid & 63;
  const int w = tid >> 6;
  const int wm = w >> 1, wn = w & 1;

  // XCD swizzle (bijective: all our grids have nwg % 8 == 0; guarded anyway)
  int bx = blockIdx.x, by = blockIdx.y;
  {
    const int nwg = gridDim.x * gridDim.y;
    if ((nwg & 7) == 0){
      const int id  = by * gridDim.x + bx;
      const int nid = (id & 7) * (nwg >> 3) + (id >> 3);
      bx = nid % gridDim.x;
      by = nid / gridDim.x;
    }
  }
  const int m0 = by * 128, n0 = bx * 128;

  f32x4 acc[4][4];
  #pragma unroll
  for (int i=0;i<4;i++)
    #pragma unroll
    for (int j=0;j<4;j++)
      acc[i][j] = (f32x4){0.f,0.f,0.f,0.f};

  const int grow = tid >> 2;            // 0..63
  const int gcol = (tid & 3) * 8;       // 0,8,16,24
  const u16* Abase = A + (size_t)(m0 + grow)*K + gcol;
  const u16* Wbase = W + (size_t)(n0 + grow)*K + gcol;
  const int lb = w*512;                 // wave-uniform LDS base (lane*16B added by HW)

  auto stage = [&](int buf, int k0){
    #pragma unroll
    for (int it=0; it<2; it++){
      __builtin_amdgcn_global_load_lds((const ASG void*)(Abase + (size_t)it*64*K + k0),
                                       (ASL void*)(&As[buf*4096 + it*2048 + lb]), 16, 0, 0);
      __builtin_amdgcn_global_load_lds((const ASG void*)(Wbase + (size_t)it*64*K + k0),
                                       (ASL void*)(&Bs[buf*4096 + it*2048 + lb]), 16, 0, 0);
    }
  };

  stage(0, 0);
  __syncthreads();
  int cbuf = 0;
  const int rr = l & 15;
  const int ko = (l >> 4) << 3;
  for (int k0 = 0; k0 < K; k0 += 32){
    if (k0 + 32 < K) stage(cbuf ^ 1, k0 + 32);
    const u16* Ac = &As[cbuf*4096];
    const u16* Bc = &Bs[cbuf*4096];
    bf16x8 af[4], bfv[4];
    #pragma unroll
    for (int f=0; f<4; f++){
      af[f]  = *(const bf16x8*)&Ac[(wm*64 + f*16 + rr)*32 + ko];
      bfv[f] = *(const bf16x8*)&Bc[(wn*64 + f*16 + rr)*32 + ko];
    }
    #pragma unroll
    for (int fi=0; fi<4; fi++)
      #pragma unroll
      for (int fj=0; fj<4; fj++)
        acc[fi][fj] = __builtin_amdgcn_mfma_f32_16x16x32_bf16(af[fi], bfv[fj], acc[fi][fj], 0, 0, 0);
    __syncthreads();                    // drains vmcnt(0): prefetched tile landed
    cbuf ^= 1;
  }

  const int cg = l & 15;
  const int rb = (l >> 4) * 4;
  #pragma unroll
  for (int fi=0; fi<4; fi++){
    #pragma unroll
    for (int r=0; r<4; r++){
      const int m = m0 + wm*64 + fi*16 + rb + r;
      #pragma unroll
      for (int fj=0; fj<4; fj++){
        const int n = n0 + wn*64 + fj*16 + cg;
        float v = acc[fi][fj][r];
        if (MODE == 0){
          if (n < DINNER)            zo[(size_t)m*DINNER + n] = f2bf(v);
          else if (n < DINNER+CONVDIM) xbcro[(size_t)m*CONVDIM + n - DINNER] = f2bf(v);
          else if (n < DPROJ)        dto[(size_t)m*NHEADS + n - (DINNER+CONVDIM)] =
                                        softplusf(v + dt_bias[n - (DINNER+CONVDIM)]);
        } else {
          xres[(size_t)m*DMODEL + n] += v;
        }
      }
    }
  }
}

// SSD (Mamba2 matrix form) with FUSED depthwise conv+SiLU on all inputs.
// One block per (batch, head). G = C·B^T (MFMA); M = mask·decay·dt·G (bf16);
// Y = M·X (MFMA); y = Y + D·x. Conv applied during LDS staging.
__global__ void __launch_bounds__(256) ssd_kernel(
  const u16* __restrict__ xbcr, const float* __restrict__ dtb,
  const float* __restrict__ cw, const float* __restrict__ cb,
  const float* __restrict__ A_log, const float* __restrict__ Dp,
  u16* __restrict__ y)
{
  const int b = blockIdx.x, h = blockIdx.y;
  const int tid = threadIdx.x;
  const int l = tid & 63;
  const int w = tid >> 6;
  const float A  = -expf(A_log[h]);
  const float Dh = Dp[h];

  __shared__ __align__(16) u16 cbm[2*128*72];       // C | B, then M reuses
  __shared__ __align__(16) u16 XtS[64*136];         // Xt[p][s] (conv'd)
  __shared__ float cum[128];
  __shared__ float dts[128];
  __shared__ float4 cwS[128];                       // conv w for B/C channels
  __shared__ float  cbS[128];
  u16* Cs = cbm;                 // [128][72]
  u16* Bq = cbm + 128*72;        // [128][72]
  u16* Ms = cbm;                 // [128][136]

  const u16* xrow = xbcr + (size_t)b*SEQ*CONVDIM;

  if (tid < 128){
    cwS[tid] = *(const float4*)&cw[(DINNER + tid)*4];
    cbS[tid] = cb[DINNER + tid];
    float a = dtb[((size_t)b*SEQ + tid)*NHEADS + h];
    dts[tid] = a;
    cum[tid] = a * A;
  }
  __syncthreads();

  // stage B (ch 768..832) and C (ch 832..896) with conv+silu
  {
    const int row0 = tid >> 3;          // 0..31
    const int col  = (tid & 7) * 8;     // 0..56
    #pragma unroll
    for (int it=0; it<4; it++){
      const int row = row0 + 32*it;
      bf16x8 tb[4], tc[4];
      #pragma unroll
      for (int k=0;k<4;k++){
        const int r = row - 3 + k;
        if (r >= 0){
          tb[k] = *(const bf16x8*)&xrow[(size_t)r*CONVDIM + DINNER + col];
          tc[k] = *(const bf16x8*)&xrow[(size_t)r*CONVDIM + DINNER + DSTATE + col];
        } else {
          tb[k] = (bf16x8){0,0,0,0,0,0,0,0};
          tc[k] = (bf16x8){0,0,0,0,0,0,0,0};
        }
      }
      bf16x8 vb, vc;
      #pragma unroll
      for (int j=0;j<8;j++){
        const float4 wb = cwS[col+j];
        const float4 wc = cwS[64+col+j];
        float ab = cbS[col+j]
                 + bf2f((u16)tb[0][j])*wb.x + bf2f((u16)tb[1][j])*wb.y
                 + bf2f((u16)tb[2][j])*wb.z + bf2f((u16)tb[3][j])*wb.w;
        float ac = cbS[64+col+j]
                 + bf2f((u16)tc[0][j])*wc.x + bf2f((u16)tc[1][j])*wc.y
                 + bf2f((u16)tc[2][j])*wc.z + bf2f((u16)tc[3][j])*wc.w;
        vb[j] = (short)f2bf(siluf(ab));
        vc[j] = (short)f2bf(siluf(ac));
      }
      *(bf16x8*)&Bq[row*72 + col] = vb;
      *(bf16x8*)&Cs[row*72 + col] = vc;
    }
  }

  // stage X transposed with rolling conv: wave w owns s in [32w, 32w+32), lane = p
  {
    const int cx = h*HEADDIM + l;
    const float4 cwx = *(const float4*)&cw[cx*4];
    const float cbx = cb[cx];
    const int sb = 32*w;
    float p3=0.f, p2=0.f, p1=0.f;       // raw[s-3], raw[s-2], raw[s-1]
    if (w > 0){
      p3 = bf2f(xrow[(size_t)(sb-3)*CONVDIM + cx]);
      p2 = bf2f(xrow[(size_t)(sb-2)*CONVDIM + cx]);
      p1 = bf2f(xrow[(size_t)(sb-1)*CONVDIM + cx]);
    }
    #pragma unroll
    for (int it=0; it<16; it++){
      const int s = sb + 2*it;
      const float r0 = bf2f(xrow[(size_t)s*CONVDIM + cx]);
      const float r1 = bf2f(xrow[(size_t)(s+1)*CONVDIM + cx]);
      const float v0 = siluf(cbx + p3*cwx.x + p2*cwx.y + p1*cwx.z + r0*cwx.w);
      const float v1 = siluf(cbx + p2*cwx.x + p1*cwx.y + r0*cwx.z + r1*cwx.w);
      const u32 pk = (u32)f2bf(v0) | ((u32)f2bf(v1) << 16);
      *(u32*)&XtS[l*136 + s] = pk;
      p3 = p1; p2 = r0; p1 = r1;
    }
  }

  // inclusive cumsum of dt*A (Hillis-Steele); also the first barrier after staging
  __syncthreads();
  for (int off=1; off<128; off<<=1){
    float v = 0.f;
    if (tid < 128 && tid >= off) v = cum[tid-off];
    __syncthreads();
    if (tid < 128) cum[tid] += v;
    __syncthreads();
  }

  // ---- G = C · B^T : wave computes rows [32w, 32w+32) x all 128 cols ----
  const int t0 = w*32;
  const int rr = l & 15;
  f32x4 g[2][8];
  #pragma unroll
  for (int i=0;i<2;i++)
    #pragma unroll
    for (int j=0;j<8;j++)
      g[i][j] = (f32x4){0.f,0.f,0.f,0.f};
  #pragma unroll
  for (int k0=0; k0<64; k0+=32){
    const int ko = k0 + ((l>>4)<<3);
    bf16x8 af[2], bfv[8];
    #pragma unroll
    for (int fi=0; fi<2; fi++) af[fi]  = *(const bf16x8*)&Cs[(t0 + 16*fi + rr)*72 + ko];
    #pragma unroll
    for (int fj=0; fj<8; fj++) bfv[fj] = *(const bf16x8*)&Bq[(16*fj + rr)*72 + ko];
    #pragma unroll
    for (int fi=0; fi<2; fi++)
      #pragma unroll
      for (int fj=0; fj<8; fj++)
        g[fi][fj] = __builtin_amdgcn_mfma_f32_16x16x32_bf16(af[fi], bfv[fj], g[fi][fj], 0, 0, 0);
  }
  __syncthreads();   // all C/B reads done; M may overwrite the region

  // ---- M[t,s] = mask * exp(cum[t]-cum[s]) * dt[s] * G ----
  {
    const int rowg = (l >> 4) * 4;
    const int colg = l & 15;
    #pragma unroll
    for (int fi=0; fi<2; fi++){
      #pragma unroll
      for (int fj=0; fj<8; fj++){
        const int s = 16*fj + colg;
        const float cs = cum[s];
        const float ds = dts[s];
        #pragma unroll
        for (int r=0; r<4; r++){
          const int t = t0 + 16*fi + rowg + r;
          float m = 0.f;
          if (t >= s) m = expf(cum[t] - cs) * ds * g[fi][fj][r];
          Ms[t*136 + s] = f2bf(m);
        }
      }
    }
  }
  __syncthreads();

  // ---- Y = M · X : rows [32w,32w+32) x 64, K = 128 ----
  f32x4 acc[2][4];
  #pragma unroll
  for (int i=0;i<2;i++)
    #pragma unroll
    for (int j=0;j<4;j++)
      acc[i][j] = (f32x4){0.f,0.f,0.f,0.f};
  #pragma unroll
  for (int k0=0; k0<128; k0+=32){
    const int ko = k0 + ((l>>4)<<3);
    bf16x8 af[2], bfv[4];
    #pragma unroll
    for (int fi=0; fi<2; fi++) af[fi]  = *(const bf16x8*)&Ms[(t0 + 16*fi + rr)*136 + ko];
    #pragma unroll
    for (int fj=0; fj<4; fj++) bfv[fj] = *(const bf16x8*)&XtS[(16*fj + rr)*136 + ko];
    #pragma unroll
    for (int fi=0; fi<2; fi++)
      #pragma unroll
      for (int fj=0; fj<4; fj++)
        acc[fi][fj] = __builtin_amdgcn_mfma_f32_16x16x32_bf16(af[fi], bfv[fj], acc[fi][fj], 0, 0, 0);
  }

  // ---- epilogue: y = Y + D*x  (conv'd x read back from XtS) ----
  {
    const int rowg = (l >> 4) * 4;
    const int colg = l & 15;
    u16* yb = y + (size_t)b*SEQ*DINNER + h*HEADDIM;
    #pragma unroll
    for (int fi=0; fi<2; fi++){
      #pragma unroll
      for (int r=0; r<4; r++){
        const int t = t0 + 16*fi + rowg + r;
        #pragma unroll
        for (int fj=0; fj<4; fj++){
          const int p = 16*fj + colg;
          const float xval = bf2f(XtS[p*136 + t]);
          yb[(size_t)t*DINNER + p] = f2bf(acc[fi][fj][r] + Dh*xval);
        }
      }
    }
  }
}

// g = y * silu(z); g *= rsqrt(mean(g^2)+eps) * norm_w  (bf16 in-place in y)
__global__ void __launch_bounds__(256) gate_rms_bf_kernel(const u16* __restrict__ z,
    const float* __restrict__ normw, u16* __restrict__ y){
  int m = blockIdx.x;
  int tid = threadIdx.x;
  float g[3];
  float ss = 0.f;
  const u16* zrow = z + (size_t)m*DINNER;
  u16* yrow = y + (size_t)m*DINNER;
  #pragma unroll
  for (int j=0;j<3;j++){
    int e = tid + 256*j;
    float zv = bf2f(zrow[e]);
    float gv = bf2f(yrow[e]) * siluf(zv);
    g[j] = gv;
    ss += gv*gv;
  }
  #pragma unroll
  for (int off=32;off;off>>=1) ss += __shfl_xor(ss,off,64);
  __shared__ float red[4];
  if ((tid&63)==0) red[tid>>6] = ss;
  __syncthreads();
  float tot = red[0]+red[1]+red[2]+red[3];
  float rms = rsqrtf(tot*(1.f/768.f) + 1e-5f);
  #pragma unroll
  for (int j=0;j<3;j++){
    int e = tid + 256*j;
    yrow[e] = f2bf(g[j]*rms*normw[e]);
  }
}

// final LN on last timestep + 60x384 projection (f32)
__global__ void __launch_bounds__(64) final_kernel(const float* __restrict__ x,
  const float* __restrict__ onw, const float* __restrict__ onb,
  const float* __restrict__ pw, const float* __restrict__ pb, float* __restrict__ out)
{
  int b = blockIdx.x;
  int lane = threadIdx.x;
  const float* row = x + ((size_t)b*SEQ + (SEQ-1))*DMODEL;
  float s=0.f, s2=0.f;
  float v[6];
  #pragma unroll
  for (int j=0;j<6;j++){ v[j] = row[lane + 64*j]; s += v[j]; s2 += v[j]*v[j]; }
  #pragma unroll
  for (int off=32;off;off>>=1){ s += __shfl_xor(s,off,64); s2 += __shfl_xor(s2,off,64); }
  float m1 = s*(1.f/384.f);
  float var = s2*(1.f/384.f) - m1*m1;
  float rstd = rsqrtf(var + 1e-5f);
  __shared__ float xn[384];
  #pragma unroll
  for (int j=0;j<6;j++){
    int d = lane + 64*j;
    xn[d] = (v[j]-m1)*rstd*onw[d] + onb[d];
  }
  __syncthreads();
  if (lane < OUTDIM){
    const float* wrow = pw + lane*DMODEL;
    float acc = pb[lane];
    #pragma unroll 4
    for (int d=0; d<DMODEL; d+=4){
      float4 xv = *(const float4*)&xn[d];
      float4 wv = *(const float4*)&wrow[d];
      acc += xv.x*wv.x + xv.y*wv.y + xv.z*wv.z + xv.w*wv.w;
    }
    out[b*OUTDIM + lane] = acc;
  }
}

extern "C" void kernel_launch(void* const* d_in, const int* in_sizes, int n_in,
                              void* d_out, int out_size, void* d_ws, size_t ws_size,
                              hipStream_t stream){
  const float* emb        = (const float*)d_in[0];
  const float* in_proj_w  = (const float*)d_in[1];
  const float* conv_w     = (const float*)d_in[2];
  const float* conv_b     = (const float*)d_in[3];
  const float* dt_bias    = (const float*)d_in[4];
  const float* A_log      = (const float*)d_in[5];
  const float* Dp         = (const float*)d_in[6];
  const float* mnw        = (const float*)d_in[7];
  const float* out_proj_w = (const float*)d_in[8];
  const float* ln_w       = (const float*)d_in[9];
  const float* ln_b       = (const float*)d_in[10];
  const float* onw        = (const float*)d_in[11];
  const float* onb        = (const float*)d_in[12];
  const float* pw         = (const float*)d_in[13];
  const float* pb         = (const float*)d_in[14];
  float* out = (float*)d_out;

  // ---- adaptive workspace ----
  // fixed: x f32, xbf bf16, wbf_in, wbf_out  (~77.5 MB)
  // per row (chunked): z 1536 + xbcr 1792 + dt 48 + y 1536 = 4912 B
  const size_t XB    = (size_t)MTOT*DMODEL*4;
  const size_t XBFB  = (size_t)MTOT*DMODEL*2;
  const size_t WINB  = (size_t)N1PAD*DMODEL*2;
  const size_t WOUTB = (size_t)DMODEL*DINNER*2;
  const size_t fixed = XB + XBFB + WINB + WOUTB;
  int CB = 256;
  while (CB > 1 && fixed + (size_t)CB*SEQ*4912ull > ws_size) CB >>= 1;
  const int Mc = CB*SEQ;
  const int nchunks = BATCH / CB;

  char* p = (char*)d_ws;
  float* x      = (float*)p;  p += XB;
  u16*   xbf    = (u16*)p;    p += XBFB;
  u16*   wbfin  = (u16*)p;    p += WINB;
  u16*   wbfout = (u16*)p;    p += WOUTB;
  u16*   z      = (u16*)p;    p += (size_t)Mc*DINNER*2;
  u16*   xbcr   = (u16*)p;    p += (size_t)Mc*CONVDIM*2;
  float* dt     = (float*)p;  p += (size_t)Mc*NHEADS*4;
  u16*   y      = (u16*)p;

  add_pe_kernel<<<MTOT*DMODEL/256,256,0,stream>>>(emb, x);
  for (int i=0;i<2;i++){
    wconv_in2_kernel<<<N1PAD*DMODEL/256,256,0,stream>>>(in_proj_w + (size_t)i*DPROJ*DMODEL, wbfin);
    wconv_out_kernel<<<DMODEL*DINNER/256,256,0,stream>>>(out_proj_w + (size_t)i*DMODEL*DINNER, wbfout);
    ln_bf_kernel<<<MTOT/4,256,0,stream>>>(x, ln_w + (size_t)i*DMODEL, ln_b + (size_t)i*DMODEL, xbf);
    for (int c=0;c<nchunks;c++){
      const u16* ac = xbf + (size_t)c*Mc*DMODEL;
      float*     xc = x   + (size_t)c*Mc*DMODEL;
      dim3 g1(N1PAD/128, Mc/128);
      gemm_bf16<0><<<g1,256,0,stream>>>(ac, wbfin, DMODEL, z, xbcr, dt,
                                        dt_bias + (size_t)i*NHEADS, nullptr);
      dim3 gs(CB, NHEADS);
      ssd_kernel<<<gs,256,0,stream>>>(xbcr, dt,
          conv_w + (size_t)i*CONVDIM*4, conv_b + (size_t)i*CONVDIM,
          A_log + (size_t)i*NHEADS, Dp + (size_t)i*NHEADS, y);
      gate_rms_bf_kernel<<<Mc,256,0,stream>>>(z, mnw + (size_t)i*DINNER, y);
      dim3 g2(DMODEL/128, Mc/128);
      gemm_bf16<1><<<g2,256,0,stream>>>(y, wbfout, DINNER, nullptr, nullptr, nullptr, nullptr, xc);
    }
  }
  final_kernel<<<BATCH,64,0,stream>>>(x, onw, onb, pw, pb, out);
}

// Round 9
// 549.225 us; speedup vs baseline: 7.4515x; 1.2395x over previous
//
#include <hip/hip_runtime.h>
#include <math.h>

#define BATCH   256
#define SEQ     128
#define DMODEL  384
#define DSTATE  64
#define DINNER  768
#define NHEADS  12
#define HEADDIM 64
#define CONVDIM 896
#define DPROJ   1676
#define N1PAD   1792
#define OUTDIM  60
#define MTOT    (BATCH*SEQ)   // 32768

typedef unsigned short u16;
typedef unsigned int   u32;
typedef short bf16x8 __attribute__((ext_vector_type(8)));
typedef float f32x4 __attribute__((ext_vector_type(4)));

#define ASG __attribute__((address_space(1)))
#define ASL __attribute__((address_space(3)))

__device__ __forceinline__ float siluf(float x){ return __fdividef(x, 1.f + __expf(-x)); }
__device__ __forceinline__ float softplusf(float x){ return fmaxf(x,0.f) + log1pf(expf(-fabsf(x))); }
__device__ __forceinline__ u16 f2bf(float x){
  union { float f; unsigned int u; } c; c.f = x;
  unsigned int r = c.u + 0x7FFFu + ((c.u >> 16) & 1u);
  return (u16)(r >> 16);
}
__device__ __forceinline__ float bf2f(u16 u){
  union { unsigned int u; float f; } c; c.u = ((unsigned int)u) << 16;
  return c.f;
}

// x = emb + positional encoding
__global__ void add_pe_kernel(const float* __restrict__ emb, float* __restrict__ x){
  int idx = blockIdx.x*256 + threadIdx.x;
  int d = idx % DMODEL;
  int l = (idx / DMODEL) % SEQ;
  int i = d >> 1;
  float div = expf((float)(2*i) * (-9.210340371976184f/384.f));
  float arg = (float)l * div;
  float pe = (d & 1) ? cosf(arg) : sinf(arg);
  x[idx] = emb[idx] + pe;
}

// weight conversions (per layer, each call)
__global__ void wconv_in2_kernel(const float* __restrict__ w, u16* __restrict__ o){
  int idx = blockIdx.x*256 + threadIdx.x;       // N1PAD*DMODEL total
  int n = idx / DMODEL, k = idx % DMODEL;
  o[idx] = (n < DPROJ) ? f2bf(w[(size_t)n*DMODEL + k]) : (u16)0;
}
__global__ void wconv_out_kernel(const float* __restrict__ w, u16* __restrict__ o){
  int idx = blockIdx.x*256 + threadIdx.x;       // 384*768 total
  o[idx] = f2bf(w[idx]);
}

// xbf = bf16( LN(x)*lnw + lnb ), one wave per row
__global__ void __launch_bounds__(256) ln_bf_kernel(const float* __restrict__ x,
    const float* __restrict__ lnw, const float* __restrict__ lnb, u16* __restrict__ xbf){
  int wave = threadIdx.x >> 6, lane = threadIdx.x & 63;
  int m = blockIdx.x*4 + wave;
  const float* row = x + (size_t)m*DMODEL;
  float v[6], s=0.f, s2=0.f;
  #pragma unroll
  for (int j=0;j<6;j++){ v[j] = row[lane + 64*j]; s += v[j]; s2 += v[j]*v[j]; }
  #pragma unroll
  for (int off=32;off;off>>=1){ s += __shfl_xor(s,off,64); s2 += __shfl_xor(s2,off,64); }
  float m1 = s * (1.f/384.f);
  float var = s2 * (1.f/384.f) - m1*m1;
  float rstd = rsqrtf(var + 1e-5f);
  u16* orow = xbf + (size_t)m*DMODEL;
  #pragma unroll
  for (int j=0;j<6;j++){
    int d = lane + 64*j;
    orow[d] = f2bf((v[j]-m1)*rstd*lnw[d] + lnb[d]);
  }
}

// bf16 MFMA GEMM, 2-phase pipelined: 128x128 tile, BK=32, double-buffered LDS.
template<int MODE>
__global__ void __launch_bounds__(256) gemm_bf16(
    const u16* __restrict__ A, const u16* __restrict__ W, const int K,
    u16* __restrict__ zo, u16* __restrict__ xbcro, float* __restrict__ dto,
    const float* __restrict__ dt_bias, float* __restrict__ xres)
{
  __shared__ __align__(16) u16 As[2*128*32];
  __shared__ __align__(16) u16 Bs[2*128*32];
  const int tid = threadIdx.x;
  const int l = tid & 63;
  const int w = tid >> 6;
  const int wm = w >> 1, wn = w & 1;

  int bx = blockIdx.x, by = blockIdx.y;
  {
    const int nwg = gridDim.x * gridDim.y;
    if ((nwg & 7) == 0){
      const int id  = by * gridDim.x + bx;
      const int nid = (id & 7) * (nwg >> 3) + (id >> 3);
      bx = nid % gridDim.x;
      by = nid / gridDim.x;
    }
  }
  const int m0 = by * 128, n0 = bx * 128;

  f32x4 acc[4][4];
  #pragma unroll
  for (int i=0;i<4;i++)
    #pragma unroll
    for (int j=0;j<4;j++)
      acc[i][j] = (f32x4){0.f,0.f,0.f,0.f};

  const int grow = tid >> 2;            // 0..63
  const int gcol = (tid & 3) * 8;       // 0,8,16,24
  const u16* Abase = A + (size_t)(m0 + grow)*K + gcol;
  const u16* Wbase = W + (size_t)(n0 + grow)*K + gcol;
  const int lb = w*512;

  auto stage = [&](int buf, int k0){
    #pragma unroll
    for (int it=0; it<2; it++){
      __builtin_amdgcn_global_load_lds((const ASG void*)(Abase + (size_t)it*64*K + k0),
                                       (ASL void*)(&As[buf*4096 + it*2048 + lb]), 16, 0, 0);
      __builtin_amdgcn_global_load_lds((const ASG void*)(Wbase + (size_t)it*64*K + k0),
                                       (ASL void*)(&Bs[buf*4096 + it*2048 + lb]), 16, 0, 0);
    }
  };

  stage(0, 0);
  __syncthreads();
  int cbuf = 0;
  const int rr = l & 15;
  const int ko = (l >> 4) << 3;
  for (int k0 = 0; k0 < K; k0 += 32){
    if (k0 + 32 < K) stage(cbuf ^ 1, k0 + 32);
    const u16* Ac = &As[cbuf*4096];
    const u16* Bc = &Bs[cbuf*4096];
    bf16x8 af[4], bfv[4];
    #pragma unroll
    for (int f=0; f<4; f++){
      af[f]  = *(const bf16x8*)&Ac[(wm*64 + f*16 + rr)*32 + ko];
      bfv[f] = *(const bf16x8*)&Bc[(wn*64 + f*16 + rr)*32 + ko];
    }
    #pragma unroll
    for (int fi=0; fi<4; fi++)
      #pragma unroll
      for (int fj=0; fj<4; fj++)
        acc[fi][fj] = __builtin_amdgcn_mfma_f32_16x16x32_bf16(af[fi], bfv[fj], acc[fi][fj], 0, 0, 0);
    __syncthreads();
    cbuf ^= 1;
  }

  const int cg = l & 15;
  const int rb = (l >> 4) * 4;
  #pragma unroll
  for (int fi=0; fi<4; fi++){
    #pragma unroll
    for (int r=0; r<4; r++){
      const int m = m0 + wm*64 + fi*16 + rb + r;
      #pragma unroll
      for (int fj=0; fj<4; fj++){
        const int n = n0 + wn*64 + fj*16 + cg;
        float v = acc[fi][fj][r];
        if (MODE == 0){
          if (n < DINNER)            zo[(size_t)m*DINNER + n] = f2bf(v);
          else if (n < DINNER+CONVDIM) xbcro[(size_t)m*CONVDIM + n - DINNER] = f2bf(v);
          else if (n < DPROJ)        dto[(size_t)m*NHEADS + n - (DINNER+CONVDIM)] =
                                        softplusf(v + dt_bias[n - (DINNER+CONVDIM)]);
        } else {
          xres[(size_t)m*DMODEL + n] += v;
        }
      }
    }
  }
}

// conv+SiLU for the shared B/C channels only (computed ONCE, not per head).
// out xbcc[row][0..63]=B', [64..127]=C'. 8 channels per thread.
__global__ void __launch_bounds__(256) conv_bc_kernel(
    const u16* __restrict__ xbcr, const float* __restrict__ cw,
    const float* __restrict__ cb, u16* __restrict__ xbcc)
{
  int idx = blockIdx.x*256 + threadIdx.x;      // Mc*16 total
  int row = idx >> 4;
  int c8  = (idx & 15) * 8;                    // 0..120 within B|C block
  int lq  = row & (SEQ-1);
  const u16* src = xbcr + (size_t)row*CONVDIM + DINNER + c8;
  bf16x8 tap[4];
  #pragma unroll
  for (int k=0;k<4;k++){
    int d = k - 3;
    if (lq + d >= 0) tap[k] = *(const bf16x8*)(src + (long)d*CONVDIM);
    else             tap[k] = (bf16x8){0,0,0,0,0,0,0,0};
  }
  bf16x8 o;
  #pragma unroll
  for (int j=0;j<8;j++){
    const float4 wv = *(const float4*)&cw[(DINNER + c8 + j)*4];
    float a = cb[DINNER + c8 + j]
            + bf2f((u16)tap[0][j])*wv.x + bf2f((u16)tap[1][j])*wv.y
            + bf2f((u16)tap[2][j])*wv.z + bf2f((u16)tap[3][j])*wv.w;
    o[j] = (short)f2bf(siluf(a));
  }
  *(bf16x8*)&xbcc[(size_t)row*128 + c8] = o;
}

// SSD (Mamba2 matrix form), one block per (batch, head).
// LDS XOR-swizzled (byte ^= (row&7)<<4). B/C pre-conv'd (xbcc); X conv fused.
// G = C·B^T (MFMA) -> M = mask·exp(cum[t]-cum[s])·dt[s]·G (bf16, reuses C/B LDS)
// -> Y = M·Xt (MFMA) -> y = Y + D·x.  3 barriers total.
__global__ void __launch_bounds__(256) ssd_kernel(
  const u16* __restrict__ xbcr, const u16* __restrict__ xbcc,
  const float* __restrict__ dtb,
  const float* __restrict__ cw, const float* __restrict__ cb,
  const float* __restrict__ A_log, const float* __restrict__ Dp,
  u16* __restrict__ y)
{
  const int b = blockIdx.x, h = blockIdx.y;
  const int tid = threadIdx.x;
  const int l = tid & 63;
  const int w = tid >> 6;
  const float A  = -__expf(A_log[h]);
  const float Dh = Dp[h];

  __shared__ __align__(16) u16 cbm[128*128];   // C[128][64]@0 | B[128][64]@16K; M[128][128] reuses
  __shared__ __align__(16) u16 XtS[64*128];    // Xt[p][s]
  __shared__ float cum[128];
  __shared__ float dts[128];
  char* Cb = (char*)cbm;
  char* Bb = (char*)cbm + 16384;
  char* Mb = (char*)cbm;
  char* Xb = (char*)XtS;

  const u16* xrow  = xbcr + (size_t)b*SEQ*CONVDIM;
  const u16* ccrow = xbcc + (size_t)b*SEQ*128;

  // wave 0: dt loads + shuffle-based inclusive cumsum of dt*A (no barriers)
  if (w == 0){
    float a0 = dtb[((size_t)b*SEQ + 2*l)*NHEADS + h];
    float a1 = dtb[((size_t)b*SEQ + 2*l+1)*NHEADS + h];
    float ps = (a0 + a1) * A;
    #pragma unroll
    for (int off=1; off<64; off<<=1){
      float v = __shfl_up(ps, off, 64);
      if (l >= off) ps += v;
    }
    float excl = ps - (a0 + a1)*A;
    cum[2*l]   = excl + a0*A;
    cum[2*l+1] = ps;
    dts[2*l]   = a0;
    dts[2*l+1] = a1;
  }

  // stage conv'd B/C: plain b128 copy into swizzled LDS
  {
    const int row0 = tid >> 4;          // 0..15
    const int colc = (tid & 15) * 8;    // 0..120
    #pragma unroll
    for (int it=0; it<8; it++){
      const int r = row0 + 16*it;
      bf16x8 v = *(const bf16x8*)&ccrow[(size_t)r*128 + colc];
      if (colc < 64) *(bf16x8*)(Bb + ((r*128 + 2*colc)      ^ ((r&7)<<4))) = v;
      else           *(bf16x8*)(Cb + ((r*128 + 2*(colc-64)) ^ ((r&7)<<4))) = v;
    }
  }

  // stage X transposed with rolling conv: wave w owns s in [32w,32w+32), lane = p
  {
    const int cx = h*HEADDIM + l;
    const float4 cwx = *(const float4*)&cw[cx*4];
    const float cbx = cb[cx];
    const int sb = 32*w;
    float p3=0.f, p2=0.f, p1=0.f;
    if (w > 0){
      p3 = bf2f(xrow[(size_t)(sb-3)*CONVDIM + cx]);
      p2 = bf2f(xrow[(size_t)(sb-2)*CONVDIM + cx]);
      p1 = bf2f(xrow[(size_t)(sb-1)*CONVDIM + cx]);
    }
    #pragma unroll
    for (int it=0; it<16; it++){
      const int s = sb + 2*it;
      const float r0 = bf2f(xrow[(size_t)s*CONVDIM + cx]);
      const float r1 = bf2f(xrow[(size_t)(s+1)*CONVDIM + cx]);
      const float v0 = siluf(cbx + p3*cwx.x + p2*cwx.y + p1*cwx.z + r0*cwx.w);
      const float v1 = siluf(cbx + p2*cwx.x + p1*cwx.y + r0*cwx.z + r1*cwx.w);
      const u32 pk = (u32)f2bf(v0) | ((u32)f2bf(v1) << 16);
      *(u32*)(Xb + ((l*256 + 2*s) ^ ((l&7)<<4))) = pk;
      p3 = p1; p2 = r0; p1 = r1;
    }
  }
  __syncthreads();

  // ---- G = C · B^T : wave w -> rows [32w,32w+32) x 128 cols ----
  const int t0 = w*32;
  const int rr = l & 15;
  const int kg = (l >> 4) << 3;
  f32x4 g[2][8];
  #pragma unroll
  for (int i=0;i<2;i++)
    #pragma unroll
    for (int j=0;j<8;j++)
      g[i][j] = (f32x4){0.f,0.f,0.f,0.f};
  #pragma unroll
  for (int k0=0; k0<64; k0+=32){
    const int ko = k0 + kg;
    bf16x8 af[2], bfv[8];
    #pragma unroll
    for (int fi=0; fi<2; fi++){
      const int r = t0 + 16*fi + rr;
      af[fi] = *(const bf16x8*)(Cb + ((r*128 + 2*ko) ^ ((r&7)<<4)));
    }
    #pragma unroll
    for (int fj=0; fj<8; fj++){
      const int r = 16*fj + rr;
      bfv[fj] = *(const bf16x8*)(Bb + ((r*128 + 2*ko) ^ ((r&7)<<4)));
    }
    #pragma unroll
    for (int fi=0; fi<2; fi++)
      #pragma unroll
      for (int fj=0; fj<8; fj++)
        g[fi][fj] = __builtin_amdgcn_mfma_f32_16x16x32_bf16(af[fi], bfv[fj], g[fi][fj], 0, 0, 0);
  }
  __syncthreads();   // C/B reads done; M may overwrite

  // ---- M[t,s] = mask * exp(cum[t]-cum[s]) * dt[s] * G ----
  {
    const int rowg = (l >> 4) * 4;
    const int colg = l & 15;
    #pragma unroll
    for (int fi=0; fi<2; fi++){
      #pragma unroll
      for (int fj=0; fj<8; fj++){
        const int s = 16*fj + colg;
        const float cs = cum[s];
        const float ds = dts[s];
        #pragma unroll
        for (int r=0; r<4; r++){
          const int t = t0 + 16*fi + rowg + r;
          float m = 0.f;
          if (t >= s) m = __expf(cum[t] - cs) * ds * g[fi][fj][r];
          *(u16*)(Mb + ((t*256 + 2*s) ^ ((t&7)<<4))) = f2bf(m);
        }
      }
    }
  }
  __syncthreads();

  // ---- Y = M · Xt : rows [32w,32w+32) x 64, K = 128 ----
  f32x4 acc[2][4];
  #pragma unroll
  for (int i=0;i<2;i++)
    #pragma unroll
    for (int j=0;j<4;j++)
      acc[i][j] = (f32x4){0.f,0.f,0.f,0.f};
  #pragma unroll
  for (int k0=0; k0<128; k0+=32){
    const int ko = k0 + kg;
    bf16x8 af[2], bfv[4];
    #pragma unroll
    for (int fi=0; fi<2; fi++){
      const int r = t0 + 16*fi + rr;
      af[fi] = *(const bf16x8*)(Mb + ((r*256 + 2*ko) ^ ((r&7)<<4)));
    }
    #pragma unroll
    for (int fj=0; fj<4; fj++){
      const int r = 16*fj + rr;
      bfv[fj] = *(const bf16x8*)(Xb + ((r*256 + 2*ko) ^ ((r&7)<<4)));
    }
    #pragma unroll
    for (int fi=0; fi<2; fi++)
      #pragma unroll
      for (int fj=0; fj<4; fj++)
        acc[fi][fj] = __builtin_amdgcn_mfma_f32_16x16x32_bf16(af[fi], bfv[fj], acc[fi][fj], 0, 0, 0);
  }

  // ---- epilogue: y = Y + D*x (conv'd x from swizzled XtS) ----
  {
    const int rowg = (l >> 4) * 4;
    const int colg = l & 15;
    u16* yb = y + (size_t)b*SEQ*DINNER + h*HEADDIM;
    #pragma unroll
    for (int fi=0; fi<2; fi++){
      #pragma unroll
      for (int r=0; r<4; r++){
        const int t = t0 + 16*fi + rowg + r;
        #pragma unroll
        for (int fj=0; fj<4; fj++){
          const int p = 16*fj + colg;
          const float xval = bf2f(*(const u16*)(Xb + ((p*256 + 2*t) ^ ((p&7)<<4))));
          yb[(size_t)t*DINNER + p] = f2bf(acc[fi][fj][r] + Dh*xval);
        }
      }
    }
  }
}

// g = y * silu(z); g *= rsqrt(mean(g^2)+eps) * norm_w  (bf16 in-place in y)
__global__ void __launch_bounds__(256) gate_rms_bf_kernel(const u16* __restrict__ z,
    const float* __restrict__ normw, u16* __restrict__ y){
  int m = blockIdx.x;
  int tid = threadIdx.x;
  float g[3];
  float ss = 0.f;
  const u16* zrow = z + (size_t)m*DINNER;
  u16* yrow = y + (size_t)m*DINNER;
  #pragma unroll
  for (int j=0;j<3;j++){
    int e = tid + 256*j;
    float zv = bf2f(zrow[e]);
    float gv = bf2f(yrow[e]) * siluf(zv);
    g[j] = gv;
    ss += gv*gv;
  }
  #pragma unroll
  for (int off=32;off;off>>=1) ss += __shfl_xor(ss,off,64);
  __shared__ float red[4];
  if ((tid&63)==0) red[tid>>6] = ss;
  __syncthreads();
  float tot = red[0]+red[1]+red[2]+red[3];
  float rms = rsqrtf(tot*(1.f/768.f) + 1e-5f);
  #pragma unroll
  for (int j=0;j<3;j++){
    int e = tid + 256*j;
    yrow[e] = f2bf(g[j]*rms*normw[e]);
  }
}

// final LN on last timestep + 60x384 projection (f32)
__global__ void __launch_bounds__(64) final_kernel(const float* __restrict__ x,
  const float* __restrict__ onw, const float* __restrict__ onb,
  const float* __restrict__ pw, const float* __restrict__ pb, float* __restrict__ out)
{
  int b = blockIdx.x;
  int lane = threadIdx.x;
  const float* row = x + ((size_t)b*SEQ + (SEQ-1))*DMODEL;
  float s=0.f, s2=0.f;
  float v[6];
  #pragma unroll
  for (int j=0;j<6;j++){ v[j] = row[lane + 64*j]; s += v[j]; s2 += v[j]*v[j]; }
  #pragma unroll
  for (int off=32;off;off>>=1){ s += __shfl_xor(s,off,64); s2 += __shfl_xor(s2,off,64); }
  float m1 = s*(1.f/384.f);
  float var = s2*(1.f/384.f) - m1*m1;
  float rstd = rsqrtf(var + 1e-5f);
  __shared__ float xn[384];
  #pragma unroll
  for (int j=0;j<6;j++){
    int d = lane + 64*j;
    xn[d] = (v[j]-m1)*rstd*onw[d] + onb[d];
  }
  __syncthreads();
  if (lane < OUTDIM){
    const float* wrow = pw + lane*DMODEL;
    float acc = pb[lane];
    #pragma unroll 4
    for (int d=0; d<DMODEL; d+=4){
      float4 xv = *(const float4*)&xn[d];
      float4 wv = *(const float4*)&wrow[d];
      acc += xv.x*wv.x + xv.y*wv.y + xv.z*wv.z + xv.w*wv.w;
    }
    out[b*OUTDIM + lane] = acc;
  }
}

extern "C" void kernel_launch(void* const* d_in, const int* in_sizes, int n_in,
                              void* d_out, int out_size, void* d_ws, size_t ws_size,
                              hipStream_t stream){
  const float* emb        = (const float*)d_in[0];
  const float* in_proj_w  = (const float*)d_in[1];
  const float* conv_w     = (const float*)d_in[2];
  const float* conv_b     = (const float*)d_in[3];
  const float* dt_bias    = (const float*)d_in[4];
  const float* A_log      = (const float*)d_in[5];
  const float* Dp         = (const float*)d_in[6];
  const float* mnw        = (const float*)d_in[7];
  const float* out_proj_w = (const float*)d_in[8];
  const float* ln_w       = (const float*)d_in[9];
  const float* ln_b       = (const float*)d_in[10];
  const float* onw        = (const float*)d_in[11];
  const float* onb        = (const float*)d_in[12];
  const float* pw         = (const float*)d_in[13];
  const float* pb         = (const float*)d_in[14];
  float* out = (float*)d_out;

  // ---- adaptive workspace ----
  // fixed: x f32, xbf bf16, wbf_in, wbf_out  (~77.5 MB)
  // per row (chunked): z 1536 + xbcr 1792 + xbcc 256 + dt 48 + y 1536 = 5168 B
  const size_t XB    = (size_t)MTOT*DMODEL*4;
  const size_t XBFB  = (size_t)MTOT*DMODEL*2;
  const size_t WINB  = (size_t)N1PAD*DMODEL*2;
  const size_t WOUTB = (size_t)DMODEL*DINNER*2;
  const size_t fixed = XB + XBFB + WINB + WOUTB;
  int CB = 256;
  while (CB > 1 && fixed + (size_t)CB*SEQ*5168ull > ws_size) CB >>= 1;
  const int Mc = CB*SEQ;
  const int nchunks = BATCH / CB;

  char* p = (char*)d_ws;
  float* x      = (float*)p;  p += XB;
  u16*   xbf    = (u16*)p;    p += XBFB;
  u16*   wbfin  = (u16*)p;    p += WINB;
  u16*   wbfout = (u16*)p;    p += WOUTB;
  u16*   z      = (u16*)p;    p += (size_t)Mc*DINNER*2;
  u16*   xbcr   = (u16*)p;    p += (size_t)Mc*CONVDIM*2;
  u16*   xbcc   = (u16*)p;    p += (size_t)Mc*128*2;
  float* dt     = (float*)p;  p += (size_t)Mc*NHEADS*4;
  u16*   y      = (u16*)p;

  add_pe_kernel<<<MTOT*DMODEL/256,256,0,stream>>>(emb, x);
  for (int i=0;i<2;i++){
    wconv_in2_kernel<<<N1PAD*DMODEL/256,256,0,stream>>>(in_proj_w + (size_t)i*DPROJ*DMODEL, wbfin);
    wconv_out_kernel<<<DMODEL*DINNER/256,256,0,stream>>>(out_proj_w + (size_t)i*DMODEL*DINNER, wbfout);
    ln_bf_kernel<<<MTOT/4,256,0,stream>>>(x, ln_w + (size_t)i*DMODEL, ln_b + (size_t)i*DMODEL, xbf);
    for (int c=0;c<nchunks;c++){
      const u16* ac = xbf + (size_t)c*Mc*DMODEL;
      float*     xc = x   + (size_t)c*Mc*DMODEL;
      dim3 g1(N1PAD/128, Mc/128);
      gemm_bf16<0><<<g1,256,0,stream>>>(ac, wbfin, DMODEL, z, xbcr, dt,
                                        dt_bias + (size_t)i*NHEADS, nullptr);
      conv_bc_kernel<<<Mc/16,256,0,stream>>>(xbcr, conv_w + (size_t)i*CONVDIM*4,
                                             conv_b + (size_t)i*CONVDIM, xbcc);
      dim3 gs(CB, NHEADS);
      ssd_kernel<<<gs,256,0,stream>>>(xbcr, xbcc, dt,
          conv_w + (size_t)i*CONVDIM*4, conv_b + (size_t)i*CONVDIM,
          A_log + (size_t)i*NHEADS, Dp + (size_t)i*NHEADS, y);
      gate_rms_bf_kernel<<<Mc,256,0,stream>>>(z, mnw + (size_t)i*DINNER, y);
      dim3 g2(DMODEL/128, Mc/128);
      gemm_bf16<1><<<g2,256,0,stream>>>(y, wbfout, DINNER, nullptr, nullptr, nullptr, nullptr, xc);
    }
  }
  final_kernel<<<BATCH,64,0,stream>>>(x, onw, onb, pw, pb, out);
}